// Round 5
// baseline (773.601 us; speedup 1.0000x reference)
//
#include <hip/hip_runtime.h>

// SAIGTransformer (f32 in/out, bf16 intermediates + MFMA GEMMs).
// ws layout (NEED = 202,375,168 B, proven previously):
//   [0,1MB): smalls: attn@64KB, ssbuf@128KB, bf16 weight copies @256KB..478KB
//   A @1MB, 151MB: xn1 (planes 192..287) -> qkv_post(288 planes bf16) -> g(255)
//     LN2 stats @A+134MB (after proj, before gate; g ends at 127.5MiB)
//   C @1MB+151MB, 48MB: per-group qkv GEMM out -> svpq(6.3MB)+spart(@+8MB,5.3MB)
//     during attention -> x2 (bf16)
// GEMM A-operands (weights, L1/L2-resident) load DIRECT from global as short8
// fragments -- no LDS staging. Gate inner loop has ZERO barriers (B staged once).

namespace {
constexpr int kB = 4;
constexpr int kC = 96;
constexpr int kHW = 65536;
constexpr int kNP = kB * kHW;
constexpr int kQKVC = 288;
constexpr int kNH = 4;
constexpr int kCH = 24;
constexpr int kQC = 27;
constexpr int kHID = 255;
constexpr int kSTR = 40;   // LDS k-stride: 32+8 pad, rows 80B (16B-aligned)
constexpr int kQKSPLIT = 32;  // pixel splits in k_qk
}

typedef __attribute__((ext_vector_type(8))) short short8;
typedef __attribute__((ext_vector_type(8))) unsigned short ushort8;
typedef __attribute__((ext_vector_type(4))) unsigned short ushortx4;
typedef __attribute__((ext_vector_type(4))) float floatx4;

__device__ __forceinline__ float bf2f(unsigned short u) {
  return __uint_as_float(((unsigned int)u) << 16);
}
__device__ __forceinline__ unsigned short f2bf(float f) {
  unsigned int i = __float_as_uint(f);
  i += 0x7fffu + ((i >> 16) & 1u);
  return (unsigned short)(i >> 16);
}

__global__ void k_zero(float* __restrict__ p, int n) {
  const int i = blockIdx.x * blockDim.x + threadIdx.x;
  if (i < n) p[i] = 0.f;
}
__global__ void k_fill0_f32(float* __restrict__ p, int n) {
  const int i = blockIdx.x * blockDim.x + threadIdx.x;
  if (i < n) p[i] = 0.f;
}

// ---- one-shot weight conversion to bf16 (padded) ----
__global__ __launch_bounds__(256) void k_wconv(
    const float* __restrict__ qkvw, const float* __restrict__ projw,
    const float* __restrict__ w1, const float* __restrict__ w2,
    const float* __restrict__ fw, unsigned short* __restrict__ qb,
    unsigned short* __restrict__ pb, unsigned short* __restrict__ w1b,
    unsigned short* __restrict__ w2b, unsigned short* __restrict__ fwb) {
  int i = blockIdx.x * 256 + threadIdx.x;
  if (i < 27648) { qb[i] = f2bf(qkvw[i]); return; }
  i -= 27648;
  if (i < 12288) {
    const int r = i >> 7, k = i & 127;
    pb[i] = (k < 108) ? f2bf(projw[r * 108 + k]) : (unsigned short)0;
    return;
  }
  i -= 12288;
  if (i < 24576) { w1b[i] = (i < 24480) ? f2bf(w1[i]) : (unsigned short)0; return; }
  i -= 24576;
  if (i < 24576) { w2b[i] = (i < 24480) ? f2bf(w2[i]) : (unsigned short)0; return; }
  i -= 24576;
  {
    const int r = i >> 8, k = i & 255;
    fwb[i] = (k < 255) ? f2bf(fw[r * 255 + k]) : (unsigned short)0;
  }
}

// ---- LN1 fused stats+apply (single pass, values held in registers) ----
__global__ __launch_bounds__(256) void k_ln1_apply(
    const float* __restrict__ x, const float* __restrict__ nw,
    const float* __restrict__ nb, unsigned short* __restrict__ A) {
  const int pg = blockIdx.x * 256 + threadIdx.x;
  const int b = pg >> 16, p = pg & (kHW - 1);
  const float* xb = x + (size_t)b * kC * kHW + p;
  float v[kC];
  float s = 0.f, s2 = 0.f;
  #pragma unroll
  for (int c = 0; c < kC; ++c) {
    v[c] = xb[(size_t)c * kHW];
    s += v[c];
    s2 = fmaf(v[c], v[c], s2);
  }
  const float m = s * (1.f / kC);
  const float var = s2 * (1.f / kC) - m * m;
  const float rstd = rsqrtf(var + 1e-5f);
  unsigned short* ob = A + ((size_t)b * kQKVC + 192) * kHW + p;
  #pragma unroll
  for (int c = 0; c < kC; ++c) {
    ob[(size_t)c * kHW] = f2bf((v[c] - m) * rstd * nw[c] + nb[c]);
  }
}

// ---- LN stats (bf16 input x2) -> mu, rstd per pixel; 8 px/thread ----
__global__ __launch_bounds__(256) void k_ln2_stats(
    const unsigned short* __restrict__ x2, float* __restrict__ mu, float* __restrict__ rs) {
  const int t8 = blockIdx.x * 256 + threadIdx.x;
  const int b = t8 >> 13, p0 = (t8 & 8191) * 8;
  const unsigned short* xb = x2 + (size_t)b * kC * kHW + p0;
  float s[8], s2[8];
  #pragma unroll
  for (int j = 0; j < 8; ++j) { s[j] = 0.f; s2[j] = 0.f; }
  for (int c = 0; c < kC; ++c) {
    const ushort8 u = *(const ushort8*)&xb[(size_t)c * kHW];
    #pragma unroll
    for (int j = 0; j < 8; ++j) {
      const float v = bf2f(u[j]);
      s[j] += v;
      s2[j] = fmaf(v, v, s2[j]);
    }
  }
  const int base = (b << 16) + p0;
  #pragma unroll
  for (int j = 0; j < 8; ++j) {
    const float m = s[j] * (1.f / kC);
    const float var = s2[j] * (1.f / kC) - m * m;
    mu[base + j] = m;
    rs[base + j] = rsqrtf(var + 1e-5f);
  }
}

// ==== GEMM 1: qkv group (M=96, K=96), A direct from global ====
__global__ __launch_bounds__(256) void k_gemm_qkv(
    const unsigned short* __restrict__ xn1base, const unsigned short* __restrict__ qb,
    int grp, unsigned short* __restrict__ bufC) {
  __shared__ __align__(16) unsigned short Bs[128 * kSTR];
  const int tid = threadIdx.x;
  const int b = blockIdx.y;
  const int p0 = blockIdx.x * 128;
  const int wave = tid >> 6, lane = tid & 63, ln16 = lane & 15, quad = lane >> 4;
  floatx4 acc[6][2];
  #pragma unroll
  for (int i = 0; i < 6; ++i) { acc[i][0] = (floatx4)(0.f); acc[i][1] = (floatx4)(0.f); }
  const int rB = tid >> 3, c0 = (tid & 7) * 16;
  const int pos = rB ^ ((tid & 3) << 3);
  const int q0 = (quad ^ ((wave * 2) & 3)) << 3;
  const int q1 = (quad ^ ((wave * 2 + 1) & 3)) << 3;
  const unsigned short* abase = qb + (size_t)(grp * 96 + ln16) * 96 + quad * 8;
  for (int ks = 0; ks < 3; ++ks) {
    const int k0 = ks * 32;
    {
      const unsigned short* src =
          xn1base + ((size_t)b * kQKVC + 192 + k0 + rB) * kHW + p0 + c0;
      const ushort8 u0 = ((const ushort8*)src)[0];
      const ushort8 u1 = ((const ushort8*)src)[1];
      #pragma unroll
      for (int e = 0; e < 8; ++e) {
        Bs[(c0 + e) * kSTR + pos] = u0[e];
        Bs[(c0 + 8 + e) * kSTR + pos] = u1[e];
      }
    }
    __syncthreads();
    short8 bfr0 = *(const short8*)&Bs[(wave * 32 + ln16) * kSTR + q0];
    short8 bfr1 = *(const short8*)&Bs[(wave * 32 + 16 + ln16) * kSTR + q1];
    #pragma unroll
    for (int ms = 0; ms < 6; ++ms) {
      const short8 afr = *(const short8*)(abase + (size_t)ms * 16 * 96 + k0);
      acc[ms][0] = __builtin_amdgcn_mfma_f32_16x16x32_bf16(afr, bfr0, acc[ms][0], 0, 0, 0);
      acc[ms][1] = __builtin_amdgcn_mfma_f32_16x16x32_bf16(afr, bfr1, acc[ms][1], 0, 0, 0);
    }
    __syncthreads();
  }
  unsigned short* ob = bufC + (size_t)b * kC * kHW;
  #pragma unroll
  for (int ms = 0; ms < 6; ++ms)
    #pragma unroll
    for (int ns = 0; ns < 2; ++ns)
      #pragma unroll
      for (int r = 0; r < 4; ++r) {
        const int R = ms * 16 + quad * 4 + r;
        const int P = p0 + wave * 32 + ns * 16 + ln16;
        ob[(size_t)R * kHW + P] = f2bf(acc[ms][ns][r]);
      }
}

// ==== GEMM 2: proj (M=96, K=108 pad 128), A direct, + x residual ====
__global__ __launch_bounds__(256) void k_gemm_proj(
    const unsigned short* __restrict__ qkv_post, const unsigned short* __restrict__ pb,
    const float* __restrict__ x, unsigned short* __restrict__ x2) {
  __shared__ __align__(16) unsigned short Bs[128 * kSTR];
  const int tid = threadIdx.x;
  const int b = blockIdx.y;
  const int p0 = blockIdx.x * 128;
  const int wave = tid >> 6, lane = tid & 63, ln16 = lane & 15, quad = lane >> 4;
  floatx4 acc[6][2];
  #pragma unroll
  for (int i = 0; i < 6; ++i) { acc[i][0] = (floatx4)(0.f); acc[i][1] = (floatx4)(0.f); }
  const int rB = tid >> 3, c0 = (tid & 7) * 16;
  const int pos = rB ^ ((tid & 3) << 3);
  const int q0 = (quad ^ ((wave * 2) & 3)) << 3;
  const int q1 = (quad ^ ((wave * 2 + 1) & 3)) << 3;
  const unsigned short* abase = pb + (size_t)ln16 * 128 + quad * 8;
  for (int ks = 0; ks < 4; ++ks) {
    const int k0 = ks * 32;
    {
      const int k = k0 + rB;
      if (k < 108) {
        const unsigned short* src = qkv_post + ((size_t)b * kQKVC + k) * kHW + p0 + c0;
        const ushort8 u0 = ((const ushort8*)src)[0];
        const ushort8 u1 = ((const ushort8*)src)[1];
        #pragma unroll
        for (int e = 0; e < 8; ++e) {
          Bs[(c0 + e) * kSTR + pos] = u0[e];
          Bs[(c0 + 8 + e) * kSTR + pos] = u1[e];
        }
      } else {
        #pragma unroll
        for (int e = 0; e < 16; ++e) Bs[(c0 + e) * kSTR + pos] = 0;
      }
    }
    __syncthreads();
    short8 bfr0 = *(const short8*)&Bs[(wave * 32 + ln16) * kSTR + q0];
    short8 bfr1 = *(const short8*)&Bs[(wave * 32 + 16 + ln16) * kSTR + q1];
    #pragma unroll
    for (int ms = 0; ms < 6; ++ms) {
      const short8 afr = *(const short8*)(abase + (size_t)ms * 16 * 128 + k0);
      acc[ms][0] = __builtin_amdgcn_mfma_f32_16x16x32_bf16(afr, bfr0, acc[ms][0], 0, 0, 0);
      acc[ms][1] = __builtin_amdgcn_mfma_f32_16x16x32_bf16(afr, bfr1, acc[ms][1], 0, 0, 0);
    }
    __syncthreads();
  }
  #pragma unroll
  for (int ms = 0; ms < 6; ++ms)
    #pragma unroll
    for (int ns = 0; ns < 2; ++ns)
      #pragma unroll
      for (int r = 0; r < 4; ++r) {
        const int R = ms * 16 + quad * 4 + r;
        const int P = p0 + wave * 32 + ns * 16 + ln16;
        const size_t idx = ((size_t)b * kC + R) * kHW + P;
        x2[idx] = f2bf(acc[ms][ns][r] + x[idx]);
      }
}

// ==== GEMM 3: ffn gate. B (128px x 96k, LN2 fused) staged ONCE; A direct.
// Inner grp/ks loops have NO barriers. ====
__global__ __launch_bounds__(256) void k_gemm_gate(
    const unsigned short* __restrict__ x2, const float* __restrict__ mu_buf,
    const float* __restrict__ rs_buf, const float* __restrict__ nw,
    const float* __restrict__ nb, const unsigned short* __restrict__ w1b,
    const unsigned short* __restrict__ w2b, unsigned short* __restrict__ g) {
  __shared__ __align__(16) unsigned short Bs[3 * 128 * kSTR];
  __shared__ float mus[128], rss[128];
  const int tid = threadIdx.x;
  const int b = blockIdx.y;
  const int p0 = blockIdx.x * 128;
  if (tid < 128) {
    mus[tid] = mu_buf[(b << 16) + p0 + tid];
    rss[tid] = rs_buf[(b << 16) + p0 + tid];
  }
  __syncthreads();
  const int wave = tid >> 6, lane = tid & 63, ln16 = lane & 15, quad = lane >> 4;
  const int rB = tid >> 3, c0 = (tid & 7) * 16;
  const int pos = rB ^ ((tid & 3) << 3);
  const int q0 = (quad ^ ((wave * 2) & 3)) << 3;
  const int q1 = (quad ^ ((wave * 2 + 1) & 3)) << 3;
  #pragma unroll
  for (int ks = 0; ks < 3; ++ks) {
    const int k = ks * 32 + rB;
    const float wk = nw[k], bk = nb[k];
    const unsigned short* src = x2 + ((size_t)b * kC + k) * kHW + p0 + c0;
    const ushort8 u0 = ((const ushort8*)src)[0];
    const ushort8 u1 = ((const ushort8*)src)[1];
    unsigned short* bp = &Bs[ks * 128 * kSTR];
    #pragma unroll
    for (int e = 0; e < 8; ++e) {
      const int n0 = c0 + e, n1 = c0 + 8 + e;
      bp[n0 * kSTR + pos] = f2bf((bf2f(u0[e]) - mus[n0]) * rss[n0] * wk + bk);
      bp[n1 * kSTR + pos] = f2bf((bf2f(u1[e]) - mus[n1]) * rss[n1] * wk + bk);
    }
  }
  __syncthreads();
  const unsigned short* a1base = w1b + (size_t)ln16 * 96 + quad * 8;
  const unsigned short* a2base = w2b + (size_t)ln16 * 96 + quad * 8;
  for (int grp = 0; grp < 4; ++grp) {
    const int i0 = grp * 64;
    floatx4 acc[8][2];
    #pragma unroll
    for (int i = 0; i < 8; ++i) { acc[i][0] = (floatx4)(0.f); acc[i][1] = (floatx4)(0.f); }
    #pragma unroll
    for (int ks = 0; ks < 3; ++ks) {
      const int k0 = ks * 32;
      const unsigned short* bp = &Bs[ks * 128 * kSTR];
      short8 bfr0 = *(const short8*)&bp[(wave * 32 + ln16) * kSTR + q0];
      short8 bfr1 = *(const short8*)&bp[(wave * 32 + 16 + ln16) * kSTR + q1];
      #pragma unroll
      for (int ms = 0; ms < 8; ++ms) {
        const unsigned short* wsrc =
            ((ms < 4) ? a1base : a2base) + (size_t)(i0 + (ms & 3) * 16) * 96 + k0;
        const short8 afr = *(const short8*)wsrc;
        acc[ms][0] = __builtin_amdgcn_mfma_f32_16x16x32_bf16(afr, bfr0, acc[ms][0], 0, 0, 0);
        acc[ms][1] = __builtin_amdgcn_mfma_f32_16x16x32_bf16(afr, bfr1, acc[ms][1], 0, 0, 0);
      }
    }
    #pragma unroll
    for (int ms = 0; ms < 4; ++ms)
      #pragma unroll
      for (int ns = 0; ns < 2; ++ns)
        #pragma unroll
        for (int r = 0; r < 4; ++r) {
          const int ii = i0 + ms * 16 + quad * 4 + r;
          if (ii < kHID) {
            const int P = p0 + wave * 32 + ns * 16 + ln16;
            const float p1 = acc[ms][ns][r], p2 = acc[ms + 4][ns][r];
            const float sig = __builtin_amdgcn_rcpf(1.f + __expf(-p2));
            const float targ = p1 * fmaf(p1 * p1, 0.0713548f, 1.5957691f);
            const float gel = p1 * __builtin_amdgcn_rcpf(1.f + __expf(-targ));
            g[((size_t)b * kHID + ii) * kHW + P] = f2bf(fmaf(p1, sig, p2 * gel));
          }
        }
  }
}

// ==== GEMM 4: ffn out (M=96, K=255 pad 256), A direct, + x2 residual ====
__global__ __launch_bounds__(256) void k_gemm_fout(
    const unsigned short* __restrict__ g, const unsigned short* __restrict__ fwb,
    const unsigned short* __restrict__ x2, float* __restrict__ out) {
  __shared__ __align__(16) unsigned short Bs[128 * kSTR];
  const int tid = threadIdx.x;
  const int b = blockIdx.y;
  const int p0 = blockIdx.x * 128;
  const int wave = tid >> 6, lane = tid & 63, ln16 = lane & 15, quad = lane >> 4;
  floatx4 acc[6][2];
  #pragma unroll
  for (int i = 0; i < 6; ++i) { acc[i][0] = (floatx4)(0.f); acc[i][1] = (floatx4)(0.f); }
  const int rB = tid >> 3, c0 = (tid & 7) * 16;
  const int pos = rB ^ ((tid & 3) << 3);
  const int q0 = (quad ^ ((wave * 2) & 3)) << 3;
  const int q1 = (quad ^ ((wave * 2 + 1) & 3)) << 3;
  const unsigned short* abase = fwb + (size_t)ln16 * 256 + quad * 8;
  for (int ks = 0; ks < 8; ++ks) {
    const int k0 = ks * 32;
    {
      const int k = k0 + rB;
      if (k < kHID) {
        const unsigned short* src = g + ((size_t)b * kHID + k) * kHW + p0 + c0;
        const ushort8 u0 = ((const ushort8*)src)[0];
        const ushort8 u1 = ((const ushort8*)src)[1];
        #pragma unroll
        for (int e = 0; e < 8; ++e) {
          Bs[(c0 + e) * kSTR + pos] = u0[e];
          Bs[(c0 + 8 + e) * kSTR + pos] = u1[e];
        }
      } else {
        #pragma unroll
        for (int e = 0; e < 16; ++e) Bs[(c0 + e) * kSTR + pos] = 0;
      }
    }
    __syncthreads();
    short8 bfr0 = *(const short8*)&Bs[(wave * 32 + ln16) * kSTR + q0];
    short8 bfr1 = *(const short8*)&Bs[(wave * 32 + 16 + ln16) * kSTR + q1];
    #pragma unroll
    for (int ms = 0; ms < 6; ++ms) {
      const short8 afr = *(const short8*)(abase + (size_t)ms * 16 * 256 + k0);
      acc[ms][0] = __builtin_amdgcn_mfma_f32_16x16x32_bf16(afr, bfr0, acc[ms][0], 0, 0, 0);
      acc[ms][1] = __builtin_amdgcn_mfma_f32_16x16x32_bf16(afr, bfr1, acc[ms][1], 0, 0, 0);
    }
    __syncthreads();
  }
  #pragma unroll
  for (int ms = 0; ms < 6; ++ms)
    #pragma unroll
    for (int ns = 0; ns < 2; ++ns)
      #pragma unroll
      for (int r = 0; r < 4; ++r) {
        const int R = ms * 16 + quad * 4 + r;
        const int P = p0 + wave * 32 + ns * 16 + ln16;
        const size_t idx = ((size_t)b * kC + R) * kHW + P;
        out[idx] = acc[ms][ns][r] + bf2f(x2[idx]);
      }
}

// ---- depthwise 3x3 SAME: 8 outputs/thread, vector row loads ----
__global__ __launch_bounds__(256) void k_dw(
    const unsigned short* __restrict__ buf, const float* __restrict__ dww,
    unsigned short* __restrict__ qkv_post, int gbase) {
  const int blk = blockIdx.x;
  const int plane = blk >> 5;            // b*kC + chl
  const int y0 = (blk & 31) * 8;
  const int b = plane / kC, chl = plane % kC;
  const int t = threadIdx.x;
  const int y = y0 + (t >> 5);
  const int x0 = (t & 31) * 8;
  const unsigned short* in = buf + (size_t)plane * kHW;
  float w[9];
  #pragma unroll
  for (int i = 0; i < 9; ++i) w[i] = dww[(size_t)(gbase + chl) * 9 + i];
  float acc[8];
  #pragma unroll
  for (int j = 0; j < 8; ++j) acc[j] = 0.f;
  #pragma unroll
  for (int dy = -1; dy <= 1; ++dy) {
    const int yy = y + dy;
    if (yy < 0 || yy > 255) continue;
    const unsigned short* rp = in + yy * 256;
    float f[10];
    const ushort8 v = *(const ushort8*)(rp + x0);
    #pragma unroll
    for (int e = 0; e < 8; ++e) f[e + 1] = bf2f(v[e]);
    f[0] = (x0 > 0) ? bf2f(rp[x0 - 1]) : 0.f;
    f[9] = (x0 < 248) ? bf2f(rp[x0 + 8]) : 0.f;
    const float w0 = w[(dy + 1) * 3], w1 = w[(dy + 1) * 3 + 1], w2 = w[(dy + 1) * 3 + 2];
    #pragma unroll
    for (int j = 0; j < 8; ++j)
      acc[j] = fmaf(w0, f[j], fmaf(w1, f[j + 1], fmaf(w2, f[j + 2], acc[j])));
  }
  unsigned short* op = qkv_post + ((size_t)b * kQKVC + gbase + chl) * kHW + y * 256 + x0;
  ushort8 o;
  #pragma unroll
  for (int j = 0; j < 8; ++j) o[j] = f2bf(acc[j]);
  *(ushort8*)op = o;
}

// ---- svp_q = svpw @ svp, bf16 planes [b*12 + j][kHW]; 8 px/thread ----
__global__ __launch_bounds__(256) void k_svpq(
    const float* __restrict__ svp, const float* __restrict__ svpw,
    unsigned short* __restrict__ svpq) {
  const int t8 = blockIdx.x * 256 + threadIdx.x;
  const int b = t8 >> 13, p0 = (t8 & 8191) * 8;
  float s0[8], s1[8], s2v[8];
  #pragma unroll
  for (int j = 0; j < 8; ++j) {
    s0[j] = svp[((size_t)b * 3 + 0) * kHW + p0 + j];
    s1[j] = svp[((size_t)b * 3 + 1) * kHW + p0 + j];
    s2v[j] = svp[((size_t)b * 3 + 2) * kHW + p0 + j];
  }
  #pragma unroll
  for (int jj = 0; jj < 12; ++jj) {
    const float w0 = svpw[jj * 3], w1 = svpw[jj * 3 + 1], w2 = svpw[jj * 3 + 2];
    ushort8 o;
    #pragma unroll
    for (int j = 0; j < 8; ++j)
      o[j] = f2bf(fmaf(w2, s2v[j], fmaf(w1, s1[j], w0 * s0[j])));
    *(ushort8*)&svpq[((size_t)b * 12 + jj) * kHW + p0] = o;
  }
}

// ---- MFMA QK^T reduction over pixels; fused row sum-of-squares (rnorm) ----
__global__ __launch_bounds__(256) void k_qk(
    const unsigned short* __restrict__ qkv_post, const unsigned short* __restrict__ svpq,
    float* __restrict__ spart, float* __restrict__ ssbuf) {
  const int bh = blockIdx.y, b = bh >> 2, h = bh & 3;
  const int tid = threadIdx.x;
  const int wave = tid >> 6, lane = tid & 63;
  const int l15 = lane & 15, gq = lane >> 4;
  const int pstart = blockIdx.x * 2048 + wave * 512;
  constexpr int NCH = 16;  // 512 px / 32

  const unsigned short* pA0 =
      qkv_post + ((size_t)b * kQKVC + h * kCH + l15) * kHW + gq * 8;
  const unsigned short* pB0 =
      qkv_post + ((size_t)b * kQKVC + 96 + h * kCH + l15) * kHW + gq * 8;
  const int rA1 = 16 + l15, rB1 = 16 + l15;
  const bool vA1 = (rA1 < kQC), vB1 = (rB1 < kCH);
  const unsigned short* pA1 =
      (rA1 < kCH) ? qkv_post + ((size_t)b * kQKVC + h * kCH + rA1) * kHW + gq * 8
      : (rA1 < kQC) ? svpq + ((size_t)(b * 12 + h * 3 + (rA1 - kCH))) * kHW + gq * 8
                    : pA0;
  const unsigned short* pB1 =
      vB1 ? qkv_post + ((size_t)b * kQKVC + 96 + h * kCH + rB1) * kHW + gq * 8 : pB0;

  floatx4 c00 = (floatx4)(0.f), c01 = (floatx4)(0.f);
  floatx4 c10 = (floatx4)(0.f), c11 = (floatx4)(0.f);
  float ssA0 = 0.f, ssA1 = 0.f, ssB0 = 0.f, ssB1 = 0.f;
  const short8 kZ = (short8)(short)0;

  short8 a0 = *(const short8*)(pA0 + pstart);
  short8 b0 = *(const short8*)(pB0 + pstart);
  short8 a1 = vA1 ? *(const short8*)(pA1 + pstart) : kZ;
  short8 b1 = vB1 ? *(const short8*)(pB1 + pstart) : kZ;
  for (int c = 0; c < NCH; ++c) {
    const short8 ta0 = a0, tb0 = b0, ta1 = a1, tb1 = b1;
    if (c + 1 < NCH) {
      const int pn = pstart + (c + 1) * 32;
      a0 = *(const short8*)(pA0 + pn);
      b0 = *(const short8*)(pB0 + pn);
      a1 = vA1 ? *(const short8*)(pA1 + pn) : kZ;
      b1 = vB1 ? *(const short8*)(pB1 + pn) : kZ;
    }
    c00 = __builtin_amdgcn_mfma_f32_16x16x32_bf16(ta0, tb0, c00, 0, 0, 0);
    c01 = __builtin_amdgcn_mfma_f32_16x16x32_bf16(ta0, tb1, c01, 0, 0, 0);
    c10 = __builtin_amdgcn_mfma_f32_16x16x32_bf16(ta1, tb0, c10, 0, 0, 0);
    c11 = __builtin_amdgcn_mfma_f32_16x16x32_bf16(ta1, tb1, c11, 0, 0, 0);
    #pragma unroll
    for (int e = 0; e < 8; ++e) {
      const float v0 = bf2f((unsigned short)ta0[e]);
      const float v1 = bf2f((unsigned short)ta1[e]);
      const float v2 = bf2f((unsigned short)tb0[e]);
      const float v3 = bf2f((unsigned short)tb1[e]);
      ssA0 = fmaf(v0, v0, ssA0);
      ssA1 = fmaf(v1, v1, ssA1);
      ssB0 = fmaf(v2, v2, ssB0);
      ssB1 = fmaf(v3, v3, ssB1);
    }
  }
  ssA0 += __shfl_xor(ssA0, 16); ssA0 += __shfl_xor(ssA0, 32);
  ssA1 += __shfl_xor(ssA1, 16); ssA1 += __shfl_xor(ssA1, 32);
  ssB0 += __shfl_xor(ssB0, 16); ssB0 += __shfl_xor(ssB0, 32);
  ssB1 += __shfl_xor(ssB1, 16); ssB1 += __shfl_xor(ssB1, 32);
  if (gq == 0) {
    atomicAdd(&ssbuf[b * 96 + h * kCH + l15], ssA0);
    if (rA1 < kCH) atomicAdd(&ssbuf[b * 96 + h * kCH + rA1], ssA1);
    else if (rA1 < kQC) atomicAdd(&ssbuf[768 + b * 12 + h * 3 + (rA1 - kCH)], ssA1);
    atomicAdd(&ssbuf[384 + b * 96 + h * kCH + l15], ssB0);
    if (vB1) atomicAdd(&ssbuf[384 + b * 96 + h * kCH + rB1], ssB1);
  }
  float* wp = spart + ((size_t)((blockIdx.x * 16 + bh) * 4 + wave)) * 648;
  #pragma unroll
  for (int r = 0; r < 4; ++r) {
    const int row0 = gq * 4 + r, row1 = 16 + gq * 4 + r;
    wp[row0 * kCH + l15] = c00[r];
    if (16 + l15 < kCH) wp[row0 * kCH + 16 + l15] = c01[r];
    if (row1 < kQC) {
      wp[row1 * kCH + l15] = c10[r];
      if (16 + l15 < kCH) wp[row1 * kCH + 16 + l15] = c11[r];
    }
  }
}

// ---- sum partials, scale by rq*rk*temp, softmax over 24 ----
__global__ __launch_bounds__(256) void k_softmax(
    const float* __restrict__ spart, const float* __restrict__ ssbuf,
    const float* __restrict__ temp, float* __restrict__ attn) {
  const int row = blockIdx.x * 256 + threadIdx.x;
  if (row >= kB * kNH * kQC) return;
  const int bh = row / kQC, c = row - bh * kQC;
  const int b = bh >> 2, h = bh & 3;
  const float ssq = (c < kCH) ? ssbuf[b * 96 + h * kCH + c]
                              : ssbuf[768 + b * 12 + h * 3 + (c - kCH)];
  const float rq = 1.f / fmaxf(sqrtf(ssq), 1e-12f);
  const float t = temp[h];
  float l[kCH];
  #pragma unroll
  for (int d = 0; d < kCH; ++d) l[d] = 0.f;
  for (int s = 0; s < kQKSPLIT * 4; ++s) {
    const int split = s >> 2, wv = s & 3;
    const float* sp = spart + ((size_t)((split * 16 + bh) * 4 + wv)) * 648 + c * kCH;
    #pragma unroll
    for (int d = 0; d < kCH; ++d) l[d] += sp[d];
  }
  float mx = -1e30f;
  #pragma unroll
  for (int d = 0; d < kCH; ++d) {
    const float rk = 1.f / fmaxf(sqrtf(ssbuf[384 + b * 96 + h * kCH + d]), 1e-12f);
    l[d] = l[d] * rq * rk * t;
    mx = fmaxf(mx, l[d]);
  }
  float sum = 0.f;
  #pragma unroll
  for (int d = 0; d < kCH; ++d) { l[d] = __expf(l[d] - mx); sum += l[d]; }
  const float inv = 1.f / sum;
  float* arow = attn + (size_t)(bh * kQC + c) * kCH;
  #pragma unroll
  for (int d = 0; d < kCH; ++d) arow[d] = l[d] * inv;
}

// ---- attn @ v -> dead q/k planes; 4 px/thread, vector loads/stores ----
__global__ __launch_bounds__(256) void k_av(
    const float* __restrict__ attn, unsigned short* __restrict__ qkv_post) {
  const int h = blockIdx.y;
  const int t4 = blockIdx.x * 256 + threadIdx.x;
  const int b = t4 >> 14, p0 = (t4 & 16383) * 4;
  __shared__ float at[kQC * kCH];
  for (int idx = threadIdx.x; idx < kQC * kCH; idx += 256)
    at[idx] = attn[(size_t)(b * kNH + h) * kQC * kCH + idx];
  __syncthreads();
  float acc[kQC][4];
  #pragma unroll
  for (int c = 0; c < kQC; ++c)
    #pragma unroll
    for (int j = 0; j < 4; ++j) acc[c][j] = 0.f;
  for (int d = 0; d < kCH; ++d) {
    const ushortx4 v =
        *(const ushortx4*)&qkv_post[((size_t)b * kQKVC + 192 + h * kCH + d) * kHW + p0];
    float vv[4];
    #pragma unroll
    for (int j = 0; j < 4; ++j) vv[j] = bf2f(v[j]);
    #pragma unroll
    for (int c = 0; c < kQC; ++c) {
      const float a = at[c * kCH + d];
      #pragma unroll
      for (int j = 0; j < 4; ++j) acc[c][j] = fmaf(a, vv[j], acc[c][j]);
    }
  }
  #pragma unroll
  for (int c = 0; c < kQC; ++c) {
    ushortx4 o;
    #pragma unroll
    for (int j = 0; j < 4; ++j) o[j] = f2bf(acc[c][j]);
    *(ushortx4*)&qkv_post[((size_t)b * kQKVC + h * kQC + c) * kHW + p0] = o;
  }
}

extern "C" void kernel_launch(void* const* d_in, const int* in_sizes, int n_in,
                              void* d_out, int out_size, void* d_ws, size_t ws_size,
                              hipStream_t stream) {
  (void)in_sizes; (void)n_in;
  const float* x     = (const float*)d_in[0];
  const float* svp   = (const float*)d_in[1];
  const float* n1w   = (const float*)d_in[2];
  const float* n1b   = (const float*)d_in[3];
  const float* qkvw  = (const float*)d_in[4];
  const float* dww   = (const float*)d_in[5];
  const float* svpw  = (const float*)d_in[6];
  const float* temp  = (const float*)d_in[7];
  const float* projw = (const float*)d_in[8];
  const float* n2w   = (const float*)d_in[9];
  const float* n2b   = (const float*)d_in[10];
  const float* w1    = (const float*)d_in[11];
  const float* w2    = (const float*)d_in[12];
  const float* fw    = (const float*)d_in[13];
  float* outp = (float*)d_out;

  const size_t SZ_A = (size_t)kB * kQKVC * kHW * 2;   // 150,994,944
  const size_t SZ_C = (size_t)kB * kC * kHW * 2;      //  50,331,648
  const size_t NEED = (1u << 20) + SZ_A + SZ_C;       // 202,375,168 (proven OK)

  if (ws_size < NEED) {
    k_fill0_f32<<<(out_size + 255) / 256, 256, 0, stream>>>(outp, out_size);
    return;
  }

  char* ws = (char*)d_ws;
  float* attn  = (float*)(ws + 65536);
  float* ssbuf = (float*)(ws + 131072);
  unsigned short* qb  = (unsigned short*)(ws + 262144);
  unsigned short* pb  = (unsigned short*)(ws + 317440);
  unsigned short* w1b = (unsigned short*)(ws + 342016);
  unsigned short* w2b = (unsigned short*)(ws + 391168);
  unsigned short* fwb = (unsigned short*)(ws + 440320);
  unsigned short* A    = (unsigned short*)(ws + (1u << 20));           // xn1/qkv_post/g
  unsigned short* bufC = (unsigned short*)(ws + (1u << 20) + SZ_A);    // group out / svpq+spart / x2
  float* mu2 = (float*)(ws + (1u << 20) + 134u * 1048576u);
  float* rs2 = (float*)(ws + (1u << 20) + 135u * 1048576u);
  unsigned short* g    = A;
  unsigned short* x2   = bufC;
  unsigned short* svpq = bufC;                                    // 6.29MB
  float* spart = (float*)(ws + (1u << 20) + SZ_A + 8u * 1048576u); // 5.3MB

  k_wconv<<<444, 256, 0, stream>>>(qkvw, projw, w1, w2, fw, qb, pb, w1b, w2b, fwb);
  k_zero<<<4, 256, 0, stream>>>(ssbuf, 816);
  k_ln1_apply<<<kNP / 256, 256, 0, stream>>>(x, n1w, n1b, A);
  for (int grp = 0; grp < 3; ++grp) {
    k_gemm_qkv<<<dim3(kHW / 128, kB), 256, 0, stream>>>(A, qb, grp, bufC);
    k_dw<<<kB * kC * 32, 256, 0, stream>>>(bufC, dww, A, grp * kC);
  }
  k_svpq<<<kNP / 8 / 256, 256, 0, stream>>>(svp, svpw, svpq);
  k_qk<<<dim3(kQKSPLIT, 16), 256, 0, stream>>>(A, svpq, spart, ssbuf);
  k_softmax<<<2, 256, 0, stream>>>(spart, ssbuf, temp, attn);
  k_av<<<dim3(kNP / 4 / 256, kNH), 256, 0, stream>>>(attn, A);
  k_gemm_proj<<<dim3(kHW / 128, kB), 256, 0, stream>>>(A, pb, x, x2);
  k_ln2_stats<<<kNP / 8 / 256, 256, 0, stream>>>(x2, mu2, rs2);
  k_gemm_gate<<<dim3(kHW / 128, kB), 256, 0, stream>>>(x2, mu2, rs2, n2w, n2b, w1b, w2b, g);
  k_gemm_fout<<<dim3(kHW / 128, kB), 256, 0, stream>>>(g, fwb, x2, outp);
}

// Round 6
// 656.121 us; speedup vs baseline: 1.1791x; 1.1791x over previous
//
#include <hip/hip_runtime.h>

// SAIGTransformer (f32 in/out, bf16 intermediates + MFMA GEMMs).
// ws layout (NEED = 202,375,168 B, proven previously):
//   [0,1MB): smalls: attn@64KB, ssbuf@128KB, bf16 weight copies @256KB..478KB
//   A @1MB, 151MB: xn1 (planes 192..287) -> qkv_post(288 planes bf16)
//     LN2 stats @A+134MB (dead v-planes of b=3 by proj time)
//   C @1MB+151MB, 48MB: per-group qkv GEMM out -> svpq(6.3MB)+spart(@+8MB,5.3MB)
//     during attention -> x2 (bf16)
// k_qk is a pure-register MFMA reduction GEMM (no LDS).
// k_dw: 8 outputs/thread via ushort8 row loads.
// R5 lesson: A-operands MUST stage via LDS (direct-global A = latency-bound, -40%).
// k_gemm_gatefout: gate's block computes ALL 255 g-rows for its 128px strip ->
//   g lives only in LDS (Gs tile per 64-row group); fout K-reduction fused in.
//   Saves 260MB HBM (g write+read). LN2 stats fused into proj epilogue.

namespace {
constexpr int kB = 4;
constexpr int kC = 96;
constexpr int kHW = 65536;
constexpr int kNP = kB * kHW;
constexpr int kQKVC = 288;
constexpr int kNH = 4;
constexpr int kCH = 24;
constexpr int kQC = 27;
constexpr int kHID = 255;
constexpr int kSTR = 40;   // LDS k-stride: 32+8 pad, rows 80B (16B-aligned)
constexpr int kGST = 72;   // Gs k-stride: 64 + 8 pad (16B-aligned rows)
constexpr int kQKSPLIT = 32;  // pixel splits in k_qk
}

typedef __attribute__((ext_vector_type(8))) short short8;
typedef __attribute__((ext_vector_type(8))) unsigned short ushort8;
typedef __attribute__((ext_vector_type(4))) unsigned short ushortx4;
typedef __attribute__((ext_vector_type(4))) float floatx4;

__device__ __forceinline__ float bf2f(unsigned short u) {
  return __uint_as_float(((unsigned int)u) << 16);
}
__device__ __forceinline__ unsigned short f2bf(float f) {
  unsigned int i = __float_as_uint(f);
  i += 0x7fffu + ((i >> 16) & 1u);
  return (unsigned short)(i >> 16);
}

__global__ void k_zero(float* __restrict__ p, int n) {
  const int i = blockIdx.x * blockDim.x + threadIdx.x;
  if (i < n) p[i] = 0.f;
}
__global__ void k_fill0_f32(float* __restrict__ p, int n) {
  const int i = blockIdx.x * blockDim.x + threadIdx.x;
  if (i < n) p[i] = 0.f;
}

// ---- one-shot weight conversion to bf16 (padded) ----
__global__ __launch_bounds__(256) void k_wconv(
    const float* __restrict__ qkvw, const float* __restrict__ projw,
    const float* __restrict__ w1, const float* __restrict__ w2,
    const float* __restrict__ fw, unsigned short* __restrict__ qb,
    unsigned short* __restrict__ pb, unsigned short* __restrict__ w1b,
    unsigned short* __restrict__ w2b, unsigned short* __restrict__ fwb) {
  int i = blockIdx.x * 256 + threadIdx.x;
  if (i < 27648) { qb[i] = f2bf(qkvw[i]); return; }
  i -= 27648;
  if (i < 12288) {
    const int r = i >> 7, k = i & 127;
    pb[i] = (k < 108) ? f2bf(projw[r * 108 + k]) : (unsigned short)0;
    return;
  }
  i -= 12288;
  if (i < 24576) { w1b[i] = (i < 24480) ? f2bf(w1[i]) : (unsigned short)0; return; }
  i -= 24576;
  if (i < 24576) { w2b[i] = (i < 24480) ? f2bf(w2[i]) : (unsigned short)0; return; }
  i -= 24576;
  {
    const int r = i >> 8, k = i & 255;
    fwb[i] = (k < 255) ? f2bf(fw[r * 255 + k]) : (unsigned short)0;
  }
}

// ---- LN1 fused stats+apply (single pass, values held in registers) ----
__global__ __launch_bounds__(256) void k_ln1_apply(
    const float* __restrict__ x, const float* __restrict__ nw,
    const float* __restrict__ nb, unsigned short* __restrict__ A) {
  const int pg = blockIdx.x * 256 + threadIdx.x;
  const int b = pg >> 16, p = pg & (kHW - 1);
  const float* xb = x + (size_t)b * kC * kHW + p;
  float v[kC];
  float s = 0.f, s2 = 0.f;
  #pragma unroll
  for (int c = 0; c < kC; ++c) {
    v[c] = xb[(size_t)c * kHW];
    s += v[c];
    s2 = fmaf(v[c], v[c], s2);
  }
  const float m = s * (1.f / kC);
  const float var = s2 * (1.f / kC) - m * m;
  const float rstd = rsqrtf(var + 1e-5f);
  unsigned short* ob = A + ((size_t)b * kQKVC + 192) * kHW + p;
  #pragma unroll
  for (int c = 0; c < kC; ++c) {
    ob[(size_t)c * kHW] = f2bf((v[c] - m) * rstd * nw[c] + nb[c]);
  }
}

// ==== GEMM 1: qkv group (M=96, K=96), B = precomputed xn1 bf16 ====
__global__ __launch_bounds__(256) void k_gemm_qkv(
    const unsigned short* __restrict__ xn1base, const unsigned short* __restrict__ qb,
    int grp, unsigned short* __restrict__ bufC) {
  __shared__ __align__(16) unsigned short As[96 * kSTR];
  __shared__ __align__(16) unsigned short Bs[128 * kSTR];
  const int tid = threadIdx.x;
  const int b = blockIdx.y;
  const int p0 = blockIdx.x * 128;
  const int wave = tid >> 6, lane = tid & 63, ln16 = lane & 15, quad = lane >> 4;
  floatx4 acc[6][2];
  #pragma unroll
  for (int i = 0; i < 6; ++i) { acc[i][0] = (floatx4)(0.f); acc[i][1] = (floatx4)(0.f); }
  const int rB = tid >> 3, c0 = (tid & 7) * 16;
  const int pos = rB ^ ((tid & 3) << 3);
  const int q0 = (quad ^ ((wave * 2) & 3)) << 3;
  const int q1 = (quad ^ ((wave * 2 + 1) & 3)) << 3;
  for (int ks = 0; ks < 3; ++ks) {
    const int k0 = ks * 32;
    for (int idx = tid; idx < 384; idx += 256) {
      const int m = idx >> 2, ch = idx & 3;
      *(short8*)&As[m * kSTR + ch * 8] =
          *(const short8*)(qb + (size_t)(grp * 96 + m) * 96 + k0 + ch * 8);
    }
    {
      const unsigned short* src =
          xn1base + ((size_t)b * kQKVC + 192 + k0 + rB) * kHW + p0 + c0;
      const ushort8 u0 = ((const ushort8*)src)[0];
      const ushort8 u1 = ((const ushort8*)src)[1];
      #pragma unroll
      for (int e = 0; e < 8; ++e) {
        Bs[(c0 + e) * kSTR + pos] = u0[e];
        Bs[(c0 + 8 + e) * kSTR + pos] = u1[e];
      }
    }
    __syncthreads();
    short8 bfr0 = *(const short8*)&Bs[(wave * 32 + ln16) * kSTR + q0];
    short8 bfr1 = *(const short8*)&Bs[(wave * 32 + 16 + ln16) * kSTR + q1];
    #pragma unroll
    for (int ms = 0; ms < 6; ++ms) {
      const short8 afr = *(const short8*)&As[(ms * 16 + ln16) * kSTR + quad * 8];
      acc[ms][0] = __builtin_amdgcn_mfma_f32_16x16x32_bf16(afr, bfr0, acc[ms][0], 0, 0, 0);
      acc[ms][1] = __builtin_amdgcn_mfma_f32_16x16x32_bf16(afr, bfr1, acc[ms][1], 0, 0, 0);
    }
    __syncthreads();
  }
  unsigned short* ob = bufC + (size_t)b * kC * kHW;
  #pragma unroll
  for (int ms = 0; ms < 6; ++ms)
    #pragma unroll
    for (int ns = 0; ns < 2; ++ns)
      #pragma unroll
      for (int r = 0; r < 4; ++r) {
        const int R = ms * 16 + quad * 4 + r;
        const int P = p0 + wave * 32 + ns * 16 + ln16;
        ob[(size_t)R * kHW + P] = f2bf(acc[ms][ns][r]);
      }
}

// ==== GEMM 2: proj (M=96, K=108 pad 128), + x residual; LN2 stats fused ====
__global__ __launch_bounds__(256) void k_gemm_proj(
    const unsigned short* __restrict__ qkv_post, const unsigned short* __restrict__ pb,
    const float* __restrict__ x, unsigned short* __restrict__ x2,
    float* __restrict__ mu2, float* __restrict__ rs2) {
  __shared__ __align__(16) unsigned short As[96 * kSTR];
  __shared__ __align__(16) unsigned short Bs[128 * kSTR];
  const int tid = threadIdx.x;
  const int b = blockIdx.y;
  const int p0 = blockIdx.x * 128;
  const int wave = tid >> 6, lane = tid & 63, ln16 = lane & 15, quad = lane >> 4;
  floatx4 acc[6][2];
  #pragma unroll
  for (int i = 0; i < 6; ++i) { acc[i][0] = (floatx4)(0.f); acc[i][1] = (floatx4)(0.f); }
  const int rB = tid >> 3, c0 = (tid & 7) * 16;
  const int pos = rB ^ ((tid & 3) << 3);
  const int q0 = (quad ^ ((wave * 2) & 3)) << 3;
  const int q1 = (quad ^ ((wave * 2 + 1) & 3)) << 3;
  for (int ks = 0; ks < 4; ++ks) {
    const int k0 = ks * 32;
    for (int idx = tid; idx < 384; idx += 256) {
      const int m = idx >> 2, ch = idx & 3;
      *(short8*)&As[m * kSTR + ch * 8] =
          *(const short8*)(pb + (size_t)m * 128 + k0 + ch * 8);
    }
    {
      const int k = k0 + rB;
      if (k < 108) {
        const unsigned short* src = qkv_post + ((size_t)b * kQKVC + k) * kHW + p0 + c0;
        const ushort8 u0 = ((const ushort8*)src)[0];
        const ushort8 u1 = ((const ushort8*)src)[1];
        #pragma unroll
        for (int e = 0; e < 8; ++e) {
          Bs[(c0 + e) * kSTR + pos] = u0[e];
          Bs[(c0 + 8 + e) * kSTR + pos] = u1[e];
        }
      } else {
        #pragma unroll
        for (int e = 0; e < 16; ++e) Bs[(c0 + e) * kSTR + pos] = 0;
      }
    }
    __syncthreads();
    short8 bfr0 = *(const short8*)&Bs[(wave * 32 + ln16) * kSTR + q0];
    short8 bfr1 = *(const short8*)&Bs[(wave * 32 + 16 + ln16) * kSTR + q1];
    #pragma unroll
    for (int ms = 0; ms < 6; ++ms) {
      const short8 afr = *(const short8*)&As[(ms * 16 + ln16) * kSTR + quad * 8];
      acc[ms][0] = __builtin_amdgcn_mfma_f32_16x16x32_bf16(afr, bfr0, acc[ms][0], 0, 0, 0);
      acc[ms][1] = __builtin_amdgcn_mfma_f32_16x16x32_bf16(afr, bfr1, acc[ms][1], 0, 0, 0);
    }
    __syncthreads();
  }
  float s[2] = {0.f, 0.f}, s2[2] = {0.f, 0.f};
  #pragma unroll
  for (int ms = 0; ms < 6; ++ms)
    #pragma unroll
    for (int ns = 0; ns < 2; ++ns)
      #pragma unroll
      for (int r = 0; r < 4; ++r) {
        const int R = ms * 16 + quad * 4 + r;
        const int P = p0 + wave * 32 + ns * 16 + ln16;
        const size_t idx = ((size_t)b * kC + R) * kHW + P;
        const float val = acc[ms][ns][r] + x[idx];
        x2[idx] = f2bf(val);
        s[ns] += val;
        s2[ns] = fmaf(val, val, s2[ns]);
      }
  // per-pixel stats: pixel P's 96 channels live in the 4 quads (same ln16,ns)
  #pragma unroll
  for (int ns = 0; ns < 2; ++ns) {
    float a = s[ns], c = s2[ns];
    a += __shfl_xor(a, 16); a += __shfl_xor(a, 32);
    c += __shfl_xor(c, 16); c += __shfl_xor(c, 32);
    if (quad == 0) {
      const int P = p0 + wave * 32 + ns * 16 + ln16;
      const float m = a * (1.f / kC);
      mu2[(b << 16) + P] = m;
      rs2[(b << 16) + P] = rsqrtf(c * (1.f / kC) - m * m + 1e-5f);
    }
  }
}

// ==== GEMM 3+4 fused: gate (M=255+1, K=96) -> Gs LDS -> fout (M=96, K=256)
// B (128px x 96k, LN2 fused) staged ONCE; per 64-row group: gate MFMA ->
// gate-epilogue into Gs -> 2x fout MFMA K-windows into persistent facc. ====
__global__ __launch_bounds__(256) void k_gemm_gatefout(
    const unsigned short* __restrict__ x2, const float* __restrict__ mu_buf,
    const float* __restrict__ rs_buf, const float* __restrict__ nw,
    const float* __restrict__ nb, const unsigned short* __restrict__ w1b,
    const unsigned short* __restrict__ w2b, const unsigned short* __restrict__ fwb,
    float* __restrict__ out) {
  __shared__ __align__(16) unsigned short Bs[3 * 128 * kSTR];  // 30720 B
  __shared__ __align__(16) unsigned short As[128 * kSTR];      // 10240 B
  __shared__ __align__(16) unsigned short Gs[128 * kGST];      // 18432 B
  __shared__ float mus[128], rss[128];
  const int tid = threadIdx.x;
  const int b = blockIdx.y;
  const int p0 = blockIdx.x * 128;
  if (tid < 128) {
    mus[tid] = mu_buf[(b << 16) + p0 + tid];
    rss[tid] = rs_buf[(b << 16) + p0 + tid];
  }
  __syncthreads();
  const int wave = tid >> 6, lane = tid & 63, ln16 = lane & 15, quad = lane >> 4;
  const int rB = tid >> 3, c0 = (tid & 7) * 16;
  const int pos = rB ^ ((tid & 3) << 3);
  const int q0 = (quad ^ ((wave * 2) & 3)) << 3;
  const int q1 = (quad ^ ((wave * 2 + 1) & 3)) << 3;
  // stage B once: all 96 k, LN2 applied
  #pragma unroll
  for (int ks = 0; ks < 3; ++ks) {
    const int k = ks * 32 + rB;
    const float wk = nw[k], bk = nb[k];
    const unsigned short* src = x2 + ((size_t)b * kC + k) * kHW + p0 + c0;
    const ushort8 u0 = ((const ushort8*)src)[0];
    const ushort8 u1 = ((const ushort8*)src)[1];
    unsigned short* bp = &Bs[ks * 128 * kSTR];
    #pragma unroll
    for (int e = 0; e < 8; ++e) {
      const int n0 = c0 + e, n1 = c0 + 8 + e;
      bp[n0 * kSTR + pos] = f2bf((bf2f(u0[e]) - mus[n0]) * rss[n0] * wk + bk);
      bp[n1 * kSTR + pos] = f2bf((bf2f(u1[e]) - mus[n1]) * rss[n1] * wk + bk);
    }
  }
  floatx4 facc[6][2];
  #pragma unroll
  for (int i = 0; i < 6; ++i) { facc[i][0] = (floatx4)(0.f); facc[i][1] = (floatx4)(0.f); }
  for (int grp = 0; grp < 4; ++grp) {
    const int i0 = grp * 64;
    floatx4 acc[8][2];
    #pragma unroll
    for (int i = 0; i < 8; ++i) { acc[i][0] = (floatx4)(0.f); acc[i][1] = (floatx4)(0.f); }
    // --- gate GEMM over K=96 ---
    #pragma unroll
    for (int ks = 0; ks < 3; ++ks) {
      for (int idx = tid; idx < 512; idx += 256) {
        const int m = idx >> 2, ch = idx & 3;
        const int ii = i0 + (m & 63);  // rows 192..255 valid: row 255 is zero
        const unsigned short* wsrc =
            ((m < 64) ? w1b : w2b) + (size_t)ii * 96 + ks * 32 + ch * 8;
        *(short8*)&As[m * kSTR + ch * 8] = *(const short8*)wsrc;
      }
      __syncthreads();  // As staged (also covers Bs on first iter / Gs free)
      const unsigned short* bp = &Bs[ks * 128 * kSTR];
      short8 bfr0 = *(const short8*)&bp[(wave * 32 + ln16) * kSTR + q0];
      short8 bfr1 = *(const short8*)&bp[(wave * 32 + 16 + ln16) * kSTR + q1];
      #pragma unroll
      for (int ms = 0; ms < 8; ++ms) {
        const short8 afr = *(const short8*)&As[(ms * 16 + ln16) * kSTR + quad * 8];
        acc[ms][0] = __builtin_amdgcn_mfma_f32_16x16x32_bf16(afr, bfr0, acc[ms][0], 0, 0, 0);
        acc[ms][1] = __builtin_amdgcn_mfma_f32_16x16x32_bf16(afr, bfr1, acc[ms][1], 0, 0, 0);
      }
      __syncthreads();  // protect As before next stage
    }
    // --- gate epilogue -> Gs (row 255 computes exactly 0) ---
    #pragma unroll
    for (int ms = 0; ms < 4; ++ms)
      #pragma unroll
      for (int ns = 0; ns < 2; ++ns)
        #pragma unroll
        for (int r = 0; r < 4; ++r) {
          const int kl = ms * 16 + quad * 4 + r;
          const int pl = wave * 32 + ns * 16 + ln16;
          const float p1 = acc[ms][ns][r], p2 = acc[ms + 4][ns][r];
          const float sig = __builtin_amdgcn_rcpf(1.f + __expf(-p2));
          const float targ = p1 * fmaf(p1 * p1, 0.0713548f, 1.5957691f);
          const float gel = p1 * __builtin_amdgcn_rcpf(1.f + __expf(-targ));
          Gs[pl * kGST + kl] = f2bf(fmaf(p1, sig, p2 * gel));
        }
    __syncthreads();  // Gs complete
    // --- fout partial: K window [i0, i0+64) from Gs ---
    #pragma unroll
    for (int ksub = 0; ksub < 2; ++ksub) {
      for (int idx = tid; idx < 384; idx += 256) {
        const int m = idx >> 2, ch = idx & 3;
        *(short8*)&As[m * kSTR + ch * 8] =
            *(const short8*)(fwb + (size_t)m * 256 + i0 + ksub * 32 + ch * 8);
      }
      __syncthreads();  // As staged
      const short8 bf0 =
          *(const short8*)&Gs[(wave * 32 + ln16) * kGST + ksub * 32 + quad * 8];
      const short8 bf1 =
          *(const short8*)&Gs[(wave * 32 + 16 + ln16) * kGST + ksub * 32 + quad * 8];
      #pragma unroll
      for (int ms = 0; ms < 6; ++ms) {
        const short8 afr = *(const short8*)&As[(ms * 16 + ln16) * kSTR + quad * 8];
        facc[ms][0] = __builtin_amdgcn_mfma_f32_16x16x32_bf16(afr, bf0, facc[ms][0], 0, 0, 0);
        facc[ms][1] = __builtin_amdgcn_mfma_f32_16x16x32_bf16(afr, bf1, facc[ms][1], 0, 0, 0);
      }
      __syncthreads();  // As/Gs free for next stage/grp
    }
  }
  // --- fout epilogue: + x2 residual, f32 out ---
  #pragma unroll
  for (int ms = 0; ms < 6; ++ms)
    #pragma unroll
    for (int ns = 0; ns < 2; ++ns)
      #pragma unroll
      for (int r = 0; r < 4; ++r) {
        const int R = ms * 16 + quad * 4 + r;
        const int P = p0 + wave * 32 + ns * 16 + ln16;
        const size_t idx = ((size_t)b * kC + R) * kHW + P;
        out[idx] = facc[ms][ns][r] + bf2f(x2[idx]);
      }
}

// ---- depthwise 3x3 SAME: 8 outputs/thread, vector row loads ----
__global__ __launch_bounds__(256) void k_dw(
    const unsigned short* __restrict__ buf, const float* __restrict__ dww,
    unsigned short* __restrict__ qkv_post, int gbase) {
  const int blk = blockIdx.x;
  const int plane = blk >> 5;            // b*kC + chl
  const int y0 = (blk & 31) * 8;
  const int b = plane / kC, chl = plane % kC;
  const int t = threadIdx.x;
  const int y = y0 + (t >> 5);
  const int x0 = (t & 31) * 8;
  const unsigned short* in = buf + (size_t)plane * kHW;
  float w[9];
  #pragma unroll
  for (int i = 0; i < 9; ++i) w[i] = dww[(size_t)(gbase + chl) * 9 + i];
  float acc[8];
  #pragma unroll
  for (int j = 0; j < 8; ++j) acc[j] = 0.f;
  #pragma unroll
  for (int dy = -1; dy <= 1; ++dy) {
    const int yy = y + dy;
    if (yy < 0 || yy > 255) continue;
    const unsigned short* rp = in + yy * 256;
    float f[10];
    const ushort8 v = *(const ushort8*)(rp + x0);
    #pragma unroll
    for (int e = 0; e < 8; ++e) f[e + 1] = bf2f(v[e]);
    f[0] = (x0 > 0) ? bf2f(rp[x0 - 1]) : 0.f;
    f[9] = (x0 < 248) ? bf2f(rp[x0 + 8]) : 0.f;
    const float w0 = w[(dy + 1) * 3], w1 = w[(dy + 1) * 3 + 1], w2 = w[(dy + 1) * 3 + 2];
    #pragma unroll
    for (int j = 0; j < 8; ++j)
      acc[j] = fmaf(w0, f[j], fmaf(w1, f[j + 1], fmaf(w2, f[j + 2], acc[j])));
  }
  unsigned short* op = qkv_post + ((size_t)b * kQKVC + gbase + chl) * kHW + y * 256 + x0;
  ushort8 o;
  #pragma unroll
  for (int j = 0; j < 8; ++j) o[j] = f2bf(acc[j]);
  *(ushort8*)op = o;
}

// ---- svp_q = svpw @ svp, bf16 planes [b*12 + j][kHW]; 8 px/thread ----
__global__ __launch_bounds__(256) void k_svpq(
    const float* __restrict__ svp, const float* __restrict__ svpw,
    unsigned short* __restrict__ svpq) {
  const int t8 = blockIdx.x * 256 + threadIdx.x;
  const int b = t8 >> 13, p0 = (t8 & 8191) * 8;
  float s0[8], s1[8], s2v[8];
  #pragma unroll
  for (int j = 0; j < 8; ++j) {
    s0[j] = svp[((size_t)b * 3 + 0) * kHW + p0 + j];
    s1[j] = svp[((size_t)b * 3 + 1) * kHW + p0 + j];
    s2v[j] = svp[((size_t)b * 3 + 2) * kHW + p0 + j];
  }
  #pragma unroll
  for (int jj = 0; jj < 12; ++jj) {
    const float w0 = svpw[jj * 3], w1 = svpw[jj * 3 + 1], w2 = svpw[jj * 3 + 2];
    ushort8 o;
    #pragma unroll
    for (int j = 0; j < 8; ++j)
      o[j] = f2bf(fmaf(w2, s2v[j], fmaf(w1, s1[j], w0 * s0[j])));
    *(ushort8*)&svpq[((size_t)b * 12 + jj) * kHW + p0] = o;
  }
}

// ---- MFMA QK^T reduction over pixels; fused row sum-of-squares (rnorm) ----
__global__ __launch_bounds__(256) void k_qk(
    const unsigned short* __restrict__ qkv_post, const unsigned short* __restrict__ svpq,
    float* __restrict__ spart, float* __restrict__ ssbuf) {
  const int bh = blockIdx.y, b = bh >> 2, h = bh & 3;
  const int tid = threadIdx.x;
  const int wave = tid >> 6, lane = tid & 63;
  const int l15 = lane & 15, gq = lane >> 4;
  const int pstart = blockIdx.x * 2048 + wave * 512;
  constexpr int NCH = 16;  // 512 px / 32

  const unsigned short* pA0 =
      qkv_post + ((size_t)b * kQKVC + h * kCH + l15) * kHW + gq * 8;
  const unsigned short* pB0 =
      qkv_post + ((size_t)b * kQKVC + 96 + h * kCH + l15) * kHW + gq * 8;
  const int rA1 = 16 + l15, rB1 = 16 + l15;
  const bool vA1 = (rA1 < kQC), vB1 = (rB1 < kCH);
  const unsigned short* pA1 =
      (rA1 < kCH) ? qkv_post + ((size_t)b * kQKVC + h * kCH + rA1) * kHW + gq * 8
      : (rA1 < kQC) ? svpq + ((size_t)(b * 12 + h * 3 + (rA1 - kCH))) * kHW + gq * 8
                    : pA0;
  const unsigned short* pB1 =
      vB1 ? qkv_post + ((size_t)b * kQKVC + 96 + h * kCH + rB1) * kHW + gq * 8 : pB0;

  floatx4 c00 = (floatx4)(0.f), c01 = (floatx4)(0.f);
  floatx4 c10 = (floatx4)(0.f), c11 = (floatx4)(0.f);
  float ssA0 = 0.f, ssA1 = 0.f, ssB0 = 0.f, ssB1 = 0.f;
  const short8 kZ = (short8)(short)0;

  short8 a0 = *(const short8*)(pA0 + pstart);
  short8 b0 = *(const short8*)(pB0 + pstart);
  short8 a1 = vA1 ? *(const short8*)(pA1 + pstart) : kZ;
  short8 b1 = vB1 ? *(const short8*)(pB1 + pstart) : kZ;
  for (int c = 0; c < NCH; ++c) {
    const short8 ta0 = a0, tb0 = b0, ta1 = a1, tb1 = b1;
    if (c + 1 < NCH) {
      const int pn = pstart + (c + 1) * 32;
      a0 = *(const short8*)(pA0 + pn);
      b0 = *(const short8*)(pB0 + pn);
      a1 = vA1 ? *(const short8*)(pA1 + pn) : kZ;
      b1 = vB1 ? *(const short8*)(pB1 + pn) : kZ;
    }
    c00 = __builtin_amdgcn_mfma_f32_16x16x32_bf16(ta0, tb0, c00, 0, 0, 0);
    c01 = __builtin_amdgcn_mfma_f32_16x16x32_bf16(ta0, tb1, c01, 0, 0, 0);
    c10 = __builtin_amdgcn_mfma_f32_16x16x32_bf16(ta1, tb0, c10, 0, 0, 0);
    c11 = __builtin_amdgcn_mfma_f32_16x16x32_bf16(ta1, tb1, c11, 0, 0, 0);
    #pragma unroll
    for (int e = 0; e < 8; ++e) {
      const float v0 = bf2f((unsigned short)ta0[e]);
      const float v1 = bf2f((unsigned short)ta1[e]);
      const float v2 = bf2f((unsigned short)tb0[e]);
      const float v3 = bf2f((unsigned short)tb1[e]);
      ssA0 = fmaf(v0, v0, ssA0);
      ssA1 = fmaf(v1, v1, ssA1);
      ssB0 = fmaf(v2, v2, ssB0);
      ssB1 = fmaf(v3, v3, ssB1);
    }
  }
  ssA0 += __shfl_xor(ssA0, 16); ssA0 += __shfl_xor(ssA0, 32);
  ssA1 += __shfl_xor(ssA1, 16); ssA1 += __shfl_xor(ssA1, 32);
  ssB0 += __shfl_xor(ssB0, 16); ssB0 += __shfl_xor(ssB0, 32);
  ssB1 += __shfl_xor(ssB1, 16); ssB1 += __shfl_xor(ssB1, 32);
  if (gq == 0) {
    atomicAdd(&ssbuf[b * 96 + h * kCH + l15], ssA0);
    if (rA1 < kCH) atomicAdd(&ssbuf[b * 96 + h * kCH + rA1], ssA1);
    else if (rA1 < kQC) atomicAdd(&ssbuf[768 + b * 12 + h * 3 + (rA1 - kCH)], ssA1);
    atomicAdd(&ssbuf[384 + b * 96 + h * kCH + l15], ssB0);
    if (vB1) atomicAdd(&ssbuf[384 + b * 96 + h * kCH + rB1], ssB1);
  }
  float* wp = spart + ((size_t)((blockIdx.x * 16 + bh) * 4 + wave)) * 648;
  #pragma unroll
  for (int r = 0; r < 4; ++r) {
    const int row0 = gq * 4 + r, row1 = 16 + gq * 4 + r;
    wp[row0 * kCH + l15] = c00[r];
    if (16 + l15 < kCH) wp[row0 * kCH + 16 + l15] = c01[r];
    if (row1 < kQC) {
      wp[row1 * kCH + l15] = c10[r];
      if (16 + l15 < kCH) wp[row1 * kCH + 16 + l15] = c11[r];
    }
  }
}

// ---- sum partials, scale by rq*rk*temp, softmax over 24 ----
__global__ __launch_bounds__(256) void k_softmax(
    const float* __restrict__ spart, const float* __restrict__ ssbuf,
    const float* __restrict__ temp, float* __restrict__ attn) {
  const int row = blockIdx.x * 256 + threadIdx.x;
  if (row >= kB * kNH * kQC) return;
  const int bh = row / kQC, c = row - bh * kQC;
  const int b = bh >> 2, h = bh & 3;
  const float ssq = (c < kCH) ? ssbuf[b * 96 + h * kCH + c]
                              : ssbuf[768 + b * 12 + h * 3 + (c - kCH)];
  const float rq = 1.f / fmaxf(sqrtf(ssq), 1e-12f);
  const float t = temp[h];
  float l[kCH];
  #pragma unroll
  for (int d = 0; d < kCH; ++d) l[d] = 0.f;
  for (int s = 0; s < kQKSPLIT * 4; ++s) {
    const int split = s >> 2, wv = s & 3;
    const float* sp = spart + ((size_t)((split * 16 + bh) * 4 + wv)) * 648 + c * kCH;
    #pragma unroll
    for (int d = 0; d < kCH; ++d) l[d] += sp[d];
  }
  float mx = -1e30f;
  #pragma unroll
  for (int d = 0; d < kCH; ++d) {
    const float rk = 1.f / fmaxf(sqrtf(ssbuf[384 + b * 96 + h * kCH + d]), 1e-12f);
    l[d] = l[d] * rq * rk * t;
    mx = fmaxf(mx, l[d]);
  }
  float sum = 0.f;
  #pragma unroll
  for (int d = 0; d < kCH; ++d) { l[d] = __expf(l[d] - mx); sum += l[d]; }
  const float inv = 1.f / sum;
  float* arow = attn + (size_t)(bh * kQC + c) * kCH;
  #pragma unroll
  for (int d = 0; d < kCH; ++d) arow[d] = l[d] * inv;
}

// ---- attn @ v -> dead q/k planes; 4 px/thread, vector loads/stores ----
__global__ __launch_bounds__(256) void k_av(
    const float* __restrict__ attn, unsigned short* __restrict__ qkv_post) {
  const int h = blockIdx.y;
  const int t4 = blockIdx.x * 256 + threadIdx.x;
  const int b = t4 >> 14, p0 = (t4 & 16383) * 4;
  __shared__ float at[kQC * kCH];
  for (int idx = threadIdx.x; idx < kQC * kCH; idx += 256)
    at[idx] = attn[(size_t)(b * kNH + h) * kQC * kCH + idx];
  __syncthreads();
  float acc[kQC][4];
  #pragma unroll
  for (int c = 0; c < kQC; ++c)
    #pragma unroll
    for (int j = 0; j < 4; ++j) acc[c][j] = 0.f;
  for (int d = 0; d < kCH; ++d) {
    const ushortx4 v =
        *(const ushortx4*)&qkv_post[((size_t)b * kQKVC + 192 + h * kCH + d) * kHW + p0];
    float vv[4];
    #pragma unroll
    for (int j = 0; j < 4; ++j) vv[j] = bf2f(v[j]);
    #pragma unroll
    for (int c = 0; c < kQC; ++c) {
      const float a = at[c * kCH + d];
      #pragma unroll
      for (int j = 0; j < 4; ++j) acc[c][j] = fmaf(a, vv[j], acc[c][j]);
    }
  }
  #pragma unroll
  for (int c = 0; c < kQC; ++c) {
    ushortx4 o;
    #pragma unroll
    for (int j = 0; j < 4; ++j) o[j] = f2bf(acc[c][j]);
    *(ushortx4*)&qkv_post[((size_t)b * kQKVC + h * kQC + c) * kHW + p0] = o;
  }
}

extern "C" void kernel_launch(void* const* d_in, const int* in_sizes, int n_in,
                              void* d_out, int out_size, void* d_ws, size_t ws_size,
                              hipStream_t stream) {
  (void)in_sizes; (void)n_in;
  const float* x     = (const float*)d_in[0];
  const float* svp   = (const float*)d_in[1];
  const float* n1w   = (const float*)d_in[2];
  const float* n1b   = (const float*)d_in[3];
  const float* qkvw  = (const float*)d_in[4];
  const float* dww   = (const float*)d_in[5];
  const float* svpw  = (const float*)d_in[6];
  const float* temp  = (const float*)d_in[7];
  const float* projw = (const float*)d_in[8];
  const float* n2w   = (const float*)d_in[9];
  const float* n2b   = (const float*)d_in[10];
  const float* w1    = (const float*)d_in[11];
  const float* w2    = (const float*)d_in[12];
  const float* fw    = (const float*)d_in[13];
  float* outp = (float*)d_out;

  const size_t SZ_A = (size_t)kB * kQKVC * kHW * 2;   // 150,994,944
  const size_t SZ_C = (size_t)kB * kC * kHW * 2;      //  50,331,648
  const size_t NEED = (1u << 20) + SZ_A + SZ_C;       // 202,375,168 (proven OK)

  if (ws_size < NEED) {
    k_fill0_f32<<<(out_size + 255) / 256, 256, 0, stream>>>(outp, out_size);
    return;
  }

  char* ws = (char*)d_ws;
  float* attn  = (float*)(ws + 65536);
  float* ssbuf = (float*)(ws + 131072);
  unsigned short* qb  = (unsigned short*)(ws + 262144);
  unsigned short* pb  = (unsigned short*)(ws + 317440);
  unsigned short* w1b = (unsigned short*)(ws + 342016);
  unsigned short* w2b = (unsigned short*)(ws + 391168);
  unsigned short* fwb = (unsigned short*)(ws + 440320);
  unsigned short* A    = (unsigned short*)(ws + (1u << 20));           // xn1/qkv_post
  unsigned short* bufC = (unsigned short*)(ws + (1u << 20) + SZ_A);    // group out / svpq+spart / x2
  float* mu2 = (float*)(ws + (1u << 20) + 134u * 1048576u);  // dead v-planes (b=3) by proj time
  float* rs2 = (float*)(ws + (1u << 20) + 135u * 1048576u);
  unsigned short* x2   = bufC;
  unsigned short* svpq = bufC;                                    // 6.29MB
  float* spart = (float*)(ws + (1u << 20) + SZ_A + 8u * 1048576u); // 5.3MB

  k_wconv<<<444, 256, 0, stream>>>(qkvw, projw, w1, w2, fw, qb, pb, w1b, w2b, fwb);
  k_zero<<<4, 256, 0, stream>>>(ssbuf, 816);
  k_ln1_apply<<<kNP / 256, 256, 0, stream>>>(x, n1w, n1b, A);
  for (int grp = 0; grp < 3; ++grp) {
    k_gemm_qkv<<<dim3(kHW / 128, kB), 256, 0, stream>>>(A, qb, grp, bufC);
    k_dw<<<kB * kC * 32, 256, 0, stream>>>(bufC, dww, A, grp * kC);
  }
  k_svpq<<<kNP / 8 / 256, 256, 0, stream>>>(svp, svpw, svpq);
  k_qk<<<dim3(kQKSPLIT, 16), 256, 0, stream>>>(A, svpq, spart, ssbuf);
  k_softmax<<<2, 256, 0, stream>>>(spart, ssbuf, temp, attn);
  k_av<<<dim3(kNP / 4 / 256, kNH), 256, 0, stream>>>(attn, A);
  k_gemm_proj<<<dim3(kHW / 128, kB), 256, 0, stream>>>(A, pb, x, x2, mu2, rs2);
  k_gemm_gatefout<<<dim3(kHW / 128, kB), 256, 0, stream>>>(
      x2, mu2, rs2, n2w, n2b, w1b, w2b, fwb, outp);
}

// Round 7
// 639.235 us; speedup vs baseline: 1.2102x; 1.0264x over previous
//
#include <hip/hip_runtime.h>

// SAIGTransformer (f32 in/out, bf16 intermediates + MFMA GEMMs).
// ws layout (NEED = 202,375,168 B, proven previously):
//   [0,1MB): smalls: attn@64KB, ssbuf@128KB, bf16 weight copies @256KB..478KB
//   A @1MB, 151MB: xn1 (planes 192..287) -> qkv_post(288 planes bf16)
//     LN2 stats @A+134MB (dead v-planes of b=3 by proj time)
//   C @1MB+151MB, 48MB: per-group qkv GEMM out -> svpq(6.3MB)+spart(@+8MB,5.3MB)
//     during attention -> x2 (bf16)
// R5 lesson: A-operands MUST stage via LDS (direct-global A = latency-bound).
// k_gemm_gatefout: g lives only in LDS; LDS=54,272B -> 3 blocks/CU.
//   Gs = [128][32] dwords, XOR block-swizzle keyed pl&7, dword-packed writes.
// k_dw: row-paired -- each thread computes rows y,y+1 (4 row loads / 16 outputs).

namespace {
constexpr int kB = 4;
constexpr int kC = 96;
constexpr int kHW = 65536;
constexpr int kNP = kB * kHW;
constexpr int kQKVC = 288;
constexpr int kNH = 4;
constexpr int kCH = 24;
constexpr int kQC = 27;
constexpr int kHID = 255;
constexpr int kSTR = 40;   // LDS k-stride: 32+8 pad, rows 80B (16B-aligned)
constexpr int kBST = 104;  // gatefout Bs stride: 96 k + 8 pad (208B rows, 16B-aligned)
constexpr int kQKSPLIT = 32;  // pixel splits in k_qk
}

typedef __attribute__((ext_vector_type(8))) short short8;
typedef __attribute__((ext_vector_type(8))) unsigned short ushort8;
typedef __attribute__((ext_vector_type(4))) unsigned short ushortx4;
typedef __attribute__((ext_vector_type(4))) float floatx4;

__device__ __forceinline__ float bf2f(unsigned short u) {
  return __uint_as_float(((unsigned int)u) << 16);
}
__device__ __forceinline__ unsigned short f2bf(float f) {
  unsigned int i = __float_as_uint(f);
  i += 0x7fffu + ((i >> 16) & 1u);
  return (unsigned short)(i >> 16);
}

__global__ void k_zero(float* __restrict__ p, int n) {
  const int i = blockIdx.x * blockDim.x + threadIdx.x;
  if (i < n) p[i] = 0.f;
}
__global__ void k_fill0_f32(float* __restrict__ p, int n) {
  const int i = blockIdx.x * blockDim.x + threadIdx.x;
  if (i < n) p[i] = 0.f;
}

// ---- one-shot weight conversion to bf16 (padded) ----
__global__ __launch_bounds__(256) void k_wconv(
    const float* __restrict__ qkvw, const float* __restrict__ projw,
    const float* __restrict__ w1, const float* __restrict__ w2,
    const float* __restrict__ fw, unsigned short* __restrict__ qb,
    unsigned short* __restrict__ pb, unsigned short* __restrict__ w1b,
    unsigned short* __restrict__ w2b, unsigned short* __restrict__ fwb) {
  int i = blockIdx.x * 256 + threadIdx.x;
  if (i < 27648) { qb[i] = f2bf(qkvw[i]); return; }
  i -= 27648;
  if (i < 12288) {
    const int r = i >> 7, k = i & 127;
    pb[i] = (k < 108) ? f2bf(projw[r * 108 + k]) : (unsigned short)0;
    return;
  }
  i -= 12288;
  if (i < 24576) { w1b[i] = (i < 24480) ? f2bf(w1[i]) : (unsigned short)0; return; }
  i -= 24576;
  if (i < 24576) { w2b[i] = (i < 24480) ? f2bf(w2[i]) : (unsigned short)0; return; }
  i -= 24576;
  {
    const int r = i >> 8, k = i & 255;
    fwb[i] = (k < 255) ? f2bf(fw[r * 255 + k]) : (unsigned short)0;
  }
}

// ---- LN1 fused stats+apply (single pass, values held in registers) ----
__global__ __launch_bounds__(256) void k_ln1_apply(
    const float* __restrict__ x, const float* __restrict__ nw,
    const float* __restrict__ nb, unsigned short* __restrict__ A) {
  const int pg = blockIdx.x * 256 + threadIdx.x;
  const int b = pg >> 16, p = pg & (kHW - 1);
  const float* xb = x + (size_t)b * kC * kHW + p;
  float v[kC];
  float s = 0.f, s2 = 0.f;
  #pragma unroll
  for (int c = 0; c < kC; ++c) {
    v[c] = xb[(size_t)c * kHW];
    s += v[c];
    s2 = fmaf(v[c], v[c], s2);
  }
  const float m = s * (1.f / kC);
  const float var = s2 * (1.f / kC) - m * m;
  const float rstd = rsqrtf(var + 1e-5f);
  unsigned short* ob = A + ((size_t)b * kQKVC + 192) * kHW + p;
  #pragma unroll
  for (int c = 0; c < kC; ++c) {
    ob[(size_t)c * kHW] = f2bf((v[c] - m) * rstd * nw[c] + nb[c]);
  }
}

// ==== GEMM 1: qkv group (M=96, K=96), B = precomputed xn1 bf16 ====
__global__ __launch_bounds__(256) void k_gemm_qkv(
    const unsigned short* __restrict__ xn1base, const unsigned short* __restrict__ qb,
    int grp, unsigned short* __restrict__ bufC) {
  __shared__ __align__(16) unsigned short As[96 * kSTR];
  __shared__ __align__(16) unsigned short Bs[128 * kSTR];
  const int tid = threadIdx.x;
  const int b = blockIdx.y;
  const int p0 = blockIdx.x * 128;
  const int wave = tid >> 6, lane = tid & 63, ln16 = lane & 15, quad = lane >> 4;
  floatx4 acc[6][2];
  #pragma unroll
  for (int i = 0; i < 6; ++i) { acc[i][0] = (floatx4)(0.f); acc[i][1] = (floatx4)(0.f); }
  const int rB = tid >> 3, c0 = (tid & 7) * 16;
  const int pos = rB ^ ((tid & 3) << 3);
  const int q0 = (quad ^ ((wave * 2) & 3)) << 3;
  const int q1 = (quad ^ ((wave * 2 + 1) & 3)) << 3;
  for (int ks = 0; ks < 3; ++ks) {
    const int k0 = ks * 32;
    for (int idx = tid; idx < 384; idx += 256) {
      const int m = idx >> 2, ch = idx & 3;
      *(short8*)&As[m * kSTR + ch * 8] =
          *(const short8*)(qb + (size_t)(grp * 96 + m) * 96 + k0 + ch * 8);
    }
    {
      const unsigned short* src =
          xn1base + ((size_t)b * kQKVC + 192 + k0 + rB) * kHW + p0 + c0;
      const ushort8 u0 = ((const ushort8*)src)[0];
      const ushort8 u1 = ((const ushort8*)src)[1];
      #pragma unroll
      for (int e = 0; e < 8; ++e) {
        Bs[(c0 + e) * kSTR + pos] = u0[e];
        Bs[(c0 + 8 + e) * kSTR + pos] = u1[e];
      }
    }
    __syncthreads();
    short8 bfr0 = *(const short8*)&Bs[(wave * 32 + ln16) * kSTR + q0];
    short8 bfr1 = *(const short8*)&Bs[(wave * 32 + 16 + ln16) * kSTR + q1];
    #pragma unroll
    for (int ms = 0; ms < 6; ++ms) {
      const short8 afr = *(const short8*)&As[(ms * 16 + ln16) * kSTR + quad * 8];
      acc[ms][0] = __builtin_amdgcn_mfma_f32_16x16x32_bf16(afr, bfr0, acc[ms][0], 0, 0, 0);
      acc[ms][1] = __builtin_amdgcn_mfma_f32_16x16x32_bf16(afr, bfr1, acc[ms][1], 0, 0, 0);
    }
    __syncthreads();
  }
  unsigned short* ob = bufC + (size_t)b * kC * kHW;
  #pragma unroll
  for (int ms = 0; ms < 6; ++ms)
    #pragma unroll
    for (int ns = 0; ns < 2; ++ns)
      #pragma unroll
      for (int r = 0; r < 4; ++r) {
        const int R = ms * 16 + quad * 4 + r;
        const int P = p0 + wave * 32 + ns * 16 + ln16;
        ob[(size_t)R * kHW + P] = f2bf(acc[ms][ns][r]);
      }
}

// ==== GEMM 2: proj (M=96, K=108 pad 128), + x residual; LN2 stats fused ====
__global__ __launch_bounds__(256) void k_gemm_proj(
    const unsigned short* __restrict__ qkv_post, const unsigned short* __restrict__ pb,
    const float* __restrict__ x, unsigned short* __restrict__ x2,
    float* __restrict__ mu2, float* __restrict__ rs2) {
  __shared__ __align__(16) unsigned short As[96 * kSTR];
  __shared__ __align__(16) unsigned short Bs[128 * kSTR];
  const int tid = threadIdx.x;
  const int b = blockIdx.y;
  const int p0 = blockIdx.x * 128;
  const int wave = tid >> 6, lane = tid & 63, ln16 = lane & 15, quad = lane >> 4;
  floatx4 acc[6][2];
  #pragma unroll
  for (int i = 0; i < 6; ++i) { acc[i][0] = (floatx4)(0.f); acc[i][1] = (floatx4)(0.f); }
  const int rB = tid >> 3, c0 = (tid & 7) * 16;
  const int pos = rB ^ ((tid & 3) << 3);
  const int q0 = (quad ^ ((wave * 2) & 3)) << 3;
  const int q1 = (quad ^ ((wave * 2 + 1) & 3)) << 3;
  for (int ks = 0; ks < 4; ++ks) {
    const int k0 = ks * 32;
    for (int idx = tid; idx < 384; idx += 256) {
      const int m = idx >> 2, ch = idx & 3;
      *(short8*)&As[m * kSTR + ch * 8] =
          *(const short8*)(pb + (size_t)m * 128 + k0 + ch * 8);
    }
    {
      const int k = k0 + rB;
      if (k < 108) {
        const unsigned short* src = qkv_post + ((size_t)b * kQKVC + k) * kHW + p0 + c0;
        const ushort8 u0 = ((const ushort8*)src)[0];
        const ushort8 u1 = ((const ushort8*)src)[1];
        #pragma unroll
        for (int e = 0; e < 8; ++e) {
          Bs[(c0 + e) * kSTR + pos] = u0[e];
          Bs[(c0 + 8 + e) * kSTR + pos] = u1[e];
        }
      } else {
        #pragma unroll
        for (int e = 0; e < 16; ++e) Bs[(c0 + e) * kSTR + pos] = 0;
      }
    }
    __syncthreads();
    short8 bfr0 = *(const short8*)&Bs[(wave * 32 + ln16) * kSTR + q0];
    short8 bfr1 = *(const short8*)&Bs[(wave * 32 + 16 + ln16) * kSTR + q1];
    #pragma unroll
    for (int ms = 0; ms < 6; ++ms) {
      const short8 afr = *(const short8*)&As[(ms * 16 + ln16) * kSTR + quad * 8];
      acc[ms][0] = __builtin_amdgcn_mfma_f32_16x16x32_bf16(afr, bfr0, acc[ms][0], 0, 0, 0);
      acc[ms][1] = __builtin_amdgcn_mfma_f32_16x16x32_bf16(afr, bfr1, acc[ms][1], 0, 0, 0);
    }
    __syncthreads();
  }
  float s[2] = {0.f, 0.f}, s2[2] = {0.f, 0.f};
  #pragma unroll
  for (int ms = 0; ms < 6; ++ms)
    #pragma unroll
    for (int ns = 0; ns < 2; ++ns)
      #pragma unroll
      for (int r = 0; r < 4; ++r) {
        const int R = ms * 16 + quad * 4 + r;
        const int P = p0 + wave * 32 + ns * 16 + ln16;
        const size_t idx = ((size_t)b * kC + R) * kHW + P;
        const float val = acc[ms][ns][r] + x[idx];
        x2[idx] = f2bf(val);
        s[ns] += val;
        s2[ns] = fmaf(val, val, s2[ns]);
      }
  #pragma unroll
  for (int ns = 0; ns < 2; ++ns) {
    float a = s[ns], c = s2[ns];
    a += __shfl_xor(a, 16); a += __shfl_xor(a, 32);
    c += __shfl_xor(c, 16); c += __shfl_xor(c, 32);
    if (quad == 0) {
      const int P = p0 + wave * 32 + ns * 16 + ln16;
      const float m = a * (1.f / kC);
      mu2[(b << 16) + P] = m;
      rs2[(b << 16) + P] = rsqrtf(c * (1.f / kC) - m * m + 1e-5f);
    }
  }
}

// ==== GEMM 3+4 fused: gate -> Gs LDS -> fout. LDS = 54,272 B (3 blocks/CU).
// Gs: [128 px][32 dwords] (2 bf16/dword), block-of-4-dword XOR swizzle keyed
// on pl&7; dword-packed writes; b128 reads land 8 lanes/bank-group (optimal).
__global__ __launch_bounds__(256) void k_gemm_gatefout(
    const unsigned short* __restrict__ x2, const float* __restrict__ mu_buf,
    const float* __restrict__ rs_buf, const float* __restrict__ nw,
    const float* __restrict__ nb, const unsigned short* __restrict__ w1b,
    const unsigned short* __restrict__ w2b, const unsigned short* __restrict__ fwb,
    float* __restrict__ out) {
  __shared__ __align__(16) unsigned short Bs[128 * kBST];  // 26624 B
  __shared__ __align__(16) unsigned short As[128 * kSTR];  // 10240 B
  __shared__ __align__(16) unsigned int Gs[128 * 32];      // 16384 B
  __shared__ float mus[128], rss[128];                     //  1024 B
  const int tid = threadIdx.x;
  const int b = blockIdx.y;
  const int p0 = blockIdx.x * 128;
  if (tid < 128) {
    mus[tid] = mu_buf[(b << 16) + p0 + tid];
    rss[tid] = rs_buf[(b << 16) + p0 + tid];
  }
  __syncthreads();
  const int wave = tid >> 6, lane = tid & 63, ln16 = lane & 15, quad = lane >> 4;
  const int rB = tid >> 3, c0 = (tid & 7) * 16;
  const int pos = rB ^ ((tid & 3) << 3);
  const int q0 = (quad ^ ((wave * 2) & 3)) << 3;
  const int q1 = (quad ^ ((wave * 2 + 1) & 3)) << 3;
  const int l7 = ln16 & 7;
  // stage B once: all 96 k, LN2 applied
  #pragma unroll
  for (int ks = 0; ks < 3; ++ks) {
    const int k = ks * 32 + rB;
    const float wk = nw[k], bk = nb[k];
    const unsigned short* src = x2 + ((size_t)b * kC + k) * kHW + p0 + c0;
    const ushort8 u0 = ((const ushort8*)src)[0];
    const ushort8 u1 = ((const ushort8*)src)[1];
    #pragma unroll
    for (int e = 0; e < 8; ++e) {
      const int n0 = c0 + e, n1 = c0 + 8 + e;
      Bs[n0 * kBST + ks * 32 + pos] = f2bf((bf2f(u0[e]) - mus[n0]) * rss[n0] * wk + bk);
      Bs[n1 * kBST + ks * 32 + pos] = f2bf((bf2f(u1[e]) - mus[n1]) * rss[n1] * wk + bk);
    }
  }
  floatx4 facc[6][2];
  #pragma unroll
  for (int i = 0; i < 6; ++i) { facc[i][0] = (floatx4)(0.f); facc[i][1] = (floatx4)(0.f); }
  for (int grp = 0; grp < 4; ++grp) {
    const int i0 = grp * 64;
    floatx4 acc[8][2];
    #pragma unroll
    for (int i = 0; i < 8; ++i) { acc[i][0] = (floatx4)(0.f); acc[i][1] = (floatx4)(0.f); }
    // --- gate GEMM over K=96 ---
    #pragma unroll
    for (int ks = 0; ks < 3; ++ks) {
      for (int idx = tid; idx < 512; idx += 256) {
        const int m = idx >> 2, ch = idx & 3;
        const int ii = i0 + (m & 63);  // rows 192..255 valid: row 255 is zero
        const unsigned short* wsrc =
            ((m < 64) ? w1b : w2b) + (size_t)ii * 96 + ks * 32 + ch * 8;
        *(short8*)&As[m * kSTR + ch * 8] = *(const short8*)wsrc;
      }
      __syncthreads();  // As staged (also covers Bs on first iter / Gs free)
      short8 bfr0 = *(const short8*)&Bs[(wave * 32 + ln16) * kBST + ks * 32 + q0];
      short8 bfr1 = *(const short8*)&Bs[(wave * 32 + 16 + ln16) * kBST + ks * 32 + q1];
      #pragma unroll
      for (int ms = 0; ms < 8; ++ms) {
        const short8 afr = *(const short8*)&As[(ms * 16 + ln16) * kSTR + quad * 8];
        acc[ms][0] = __builtin_amdgcn_mfma_f32_16x16x32_bf16(afr, bfr0, acc[ms][0], 0, 0, 0);
        acc[ms][1] = __builtin_amdgcn_mfma_f32_16x16x32_bf16(afr, bfr1, acc[ms][1], 0, 0, 0);
      }
      __syncthreads();  // protect As before next stage
    }
    // --- gate epilogue -> Gs (dword-packed, block-swizzled; row 255 -> 0) ---
    #pragma unroll
    for (int ms = 0; ms < 4; ++ms)
      #pragma unroll
      for (int ns = 0; ns < 2; ++ns) {
        const int pl = wave * 32 + ns * 16 + ln16;
        #pragma unroll
        for (int rr = 0; rr < 2; ++rr) {
          float gv[2];
          #pragma unroll
          for (int h = 0; h < 2; ++h) {
            const float p1 = acc[ms][ns][rr * 2 + h], p2 = acc[ms + 4][ns][rr * 2 + h];
            const float sig = __builtin_amdgcn_rcpf(1.f + __expf(-p2));
            const float targ = p1 * fmaf(p1 * p1, 0.0713548f, 1.5957691f);
            const float gel = p1 * __builtin_amdgcn_rcpf(1.f + __expf(-targ));
            gv[h] = fmaf(p1, sig, p2 * gel);
          }
          const int dj = ms * 8 + quad * 2 + rr;       // dword idx in row (0..31)
          const int djs = dj ^ (l7 << 2);              // swizzle 4-dword blocks
          Gs[pl * 32 + djs] = (unsigned int)f2bf(gv[0]) | ((unsigned int)f2bf(gv[1]) << 16);
        }
      }
    __syncthreads();  // Gs complete
    // --- fout partial: K window [i0, i0+64) from Gs ---
    #pragma unroll
    for (int ksub = 0; ksub < 2; ++ksub) {
      for (int idx = tid; idx < 384; idx += 256) {
        const int m = idx >> 2, ch = idx & 3;
        *(short8*)&As[m * kSTR + ch * 8] =
            *(const short8*)(fwb + (size_t)m * 256 + i0 + ksub * 32 + ch * 8);
      }
      __syncthreads();  // As staged
      const int bka = ((ksub * 4 + quad) ^ l7) * 4;
      const short8 bf0 = *(const short8*)&Gs[(wave * 32 + ln16) * 32 + bka];
      const short8 bf1 = *(const short8*)&Gs[(wave * 32 + 16 + ln16) * 32 + bka];
      #pragma unroll
      for (int ms = 0; ms < 6; ++ms) {
        const short8 afr = *(const short8*)&As[(ms * 16 + ln16) * kSTR + quad * 8];
        facc[ms][0] = __builtin_amdgcn_mfma_f32_16x16x32_bf16(afr, bf0, facc[ms][0], 0, 0, 0);
        facc[ms][1] = __builtin_amdgcn_mfma_f32_16x16x32_bf16(afr, bf1, facc[ms][1], 0, 0, 0);
      }
      __syncthreads();  // As/Gs free for next stage/grp
    }
  }
  // --- fout epilogue: + x2 residual, f32 out ---
  #pragma unroll
  for (int ms = 0; ms < 6; ++ms)
    #pragma unroll
    for (int ns = 0; ns < 2; ++ns)
      #pragma unroll
      for (int r = 0; r < 4; ++r) {
        const int R = ms * 16 + quad * 4 + r;
        const int P = p0 + wave * 32 + ns * 16 + ln16;
        const size_t idx = ((size_t)b * kC + R) * kHW + P;
        out[idx] = facc[ms][ns][r] + bf2f(x2[idx]);
      }
}

// ---- depthwise 3x3 SAME: 16 outputs/thread (rows y,y+1 x 8 px) ----
// 4 row loads serve both output rows. grid = 384 planes * 16 row-groups.
__global__ __launch_bounds__(256) void k_dw(
    const unsigned short* __restrict__ buf, const float* __restrict__ dww,
    unsigned short* __restrict__ qkv_post, int gbase) {
  const int blk = blockIdx.x;
  const int plane = blk >> 4;            // b*kC + chl
  const int yg = (blk & 15) * 16;
  const int b = plane / kC, chl = plane % kC;
  const int t = threadIdx.x;
  const int y = yg + (t >> 5) * 2;       // rows y, y+1
  const int x0 = (t & 31) * 8;
  const unsigned short* in = buf + (size_t)plane * kHW;
  float w[9];
  #pragma unroll
  for (int i = 0; i < 9; ++i) w[i] = dww[(size_t)(gbase + chl) * 9 + i];
  float acc0[8], acc1[8];
  #pragma unroll
  for (int j = 0; j < 8; ++j) { acc0[j] = 0.f; acc1[j] = 0.f; }
  #pragma unroll
  for (int dy = -1; dy <= 2; ++dy) {
    const int yy = y + dy;
    if (yy < 0 || yy > 255) continue;
    const unsigned short* rp = in + yy * 256;
    float f[10];
    const ushort8 v = *(const ushort8*)(rp + x0);
    #pragma unroll
    for (int e = 0; e < 8; ++e) f[e + 1] = bf2f(v[e]);
    f[0] = (x0 > 0) ? bf2f(rp[x0 - 1]) : 0.f;
    f[9] = (x0 < 248) ? bf2f(rp[x0 + 8]) : 0.f;
    if (dy <= 1) {  // contributes to row y with weight-row dy+1
      const float w0 = w[(dy + 1) * 3], w1 = w[(dy + 1) * 3 + 1], w2 = w[(dy + 1) * 3 + 2];
      #pragma unroll
      for (int j = 0; j < 8; ++j)
        acc0[j] = fmaf(w0, f[j], fmaf(w1, f[j + 1], fmaf(w2, f[j + 2], acc0[j])));
    }
    if (dy >= 0) {  // contributes to row y+1 with weight-row dy
      const float w0 = w[dy * 3], w1 = w[dy * 3 + 1], w2 = w[dy * 3 + 2];
      #pragma unroll
      for (int j = 0; j < 8; ++j)
        acc1[j] = fmaf(w0, f[j], fmaf(w1, f[j + 1], fmaf(w2, f[j + 2], acc1[j])));
    }
  }
  unsigned short* op = qkv_post + ((size_t)b * kQKVC + gbase + chl) * kHW + y * 256 + x0;
  ushort8 o0, o1;
  #pragma unroll
  for (int j = 0; j < 8; ++j) { o0[j] = f2bf(acc0[j]); o1[j] = f2bf(acc1[j]); }
  *(ushort8*)op = o0;
  *(ushort8*)(op + 256) = o1;
}

// ---- svp_q = svpw @ svp, bf16 planes [b*12 + j][kHW]; 8 px/thread ----
__global__ __launch_bounds__(256) void k_svpq(
    const float* __restrict__ svp, const float* __restrict__ svpw,
    unsigned short* __restrict__ svpq) {
  const int t8 = blockIdx.x * 256 + threadIdx.x;
  const int b = t8 >> 13, p0 = (t8 & 8191) * 8;
  float s0[8], s1[8], s2v[8];
  #pragma unroll
  for (int j = 0; j < 8; ++j) {
    s0[j] = svp[((size_t)b * 3 + 0) * kHW + p0 + j];
    s1[j] = svp[((size_t)b * 3 + 1) * kHW + p0 + j];
    s2v[j] = svp[((size_t)b * 3 + 2) * kHW + p0 + j];
  }
  #pragma unroll
  for (int jj = 0; jj < 12; ++jj) {
    const float w0 = svpw[jj * 3], w1 = svpw[jj * 3 + 1], w2 = svpw[jj * 3 + 2];
    ushort8 o;
    #pragma unroll
    for (int j = 0; j < 8; ++j)
      o[j] = f2bf(fmaf(w2, s2v[j], fmaf(w1, s1[j], w0 * s0[j])));
    *(ushort8*)&svpq[((size_t)b * 12 + jj) * kHW + p0] = o;
  }
}

// ---- MFMA QK^T reduction over pixels; fused row sum-of-squares (rnorm) ----
__global__ __launch_bounds__(256) void k_qk(
    const unsigned short* __restrict__ qkv_post, const unsigned short* __restrict__ svpq,
    float* __restrict__ spart, float* __restrict__ ssbuf) {
  const int bh = blockIdx.y, b = bh >> 2, h = bh & 3;
  const int tid = threadIdx.x;
  const int wave = tid >> 6, lane = tid & 63;
  const int l15 = lane & 15, gq = lane >> 4;
  const int pstart = blockIdx.x * 2048 + wave * 512;
  constexpr int NCH = 16;  // 512 px / 32

  const unsigned short* pA0 =
      qkv_post + ((size_t)b * kQKVC + h * kCH + l15) * kHW + gq * 8;
  const unsigned short* pB0 =
      qkv_post + ((size_t)b * kQKVC + 96 + h * kCH + l15) * kHW + gq * 8;
  const int rA1 = 16 + l15, rB1 = 16 + l15;
  const bool vA1 = (rA1 < kQC), vB1 = (rB1 < kCH);
  const unsigned short* pA1 =
      (rA1 < kCH) ? qkv_post + ((size_t)b * kQKVC + h * kCH + rA1) * kHW + gq * 8
      : (rA1 < kQC) ? svpq + ((size_t)(b * 12 + h * 3 + (rA1 - kCH))) * kHW + gq * 8
                    : pA0;
  const unsigned short* pB1 =
      vB1 ? qkv_post + ((size_t)b * kQKVC + 96 + h * kCH + rB1) * kHW + gq * 8 : pB0;

  floatx4 c00 = (floatx4)(0.f), c01 = (floatx4)(0.f);
  floatx4 c10 = (floatx4)(0.f), c11 = (floatx4)(0.f);
  float ssA0 = 0.f, ssA1 = 0.f, ssB0 = 0.f, ssB1 = 0.f;
  const short8 kZ = (short8)(short)0;

  short8 a0 = *(const short8*)(pA0 + pstart);
  short8 b0 = *(const short8*)(pB0 + pstart);
  short8 a1 = vA1 ? *(const short8*)(pA1 + pstart) : kZ;
  short8 b1 = vB1 ? *(const short8*)(pB1 + pstart) : kZ;
  for (int c = 0; c < NCH; ++c) {
    const short8 ta0 = a0, tb0 = b0, ta1 = a1, tb1 = b1;
    if (c + 1 < NCH) {
      const int pn = pstart + (c + 1) * 32;
      a0 = *(const short8*)(pA0 + pn);
      b0 = *(const short8*)(pB0 + pn);
      a1 = vA1 ? *(const short8*)(pA1 + pn) : kZ;
      b1 = vB1 ? *(const short8*)(pB1 + pn) : kZ;
    }
    c00 = __builtin_amdgcn_mfma_f32_16x16x32_bf16(ta0, tb0, c00, 0, 0, 0);
    c01 = __builtin_amdgcn_mfma_f32_16x16x32_bf16(ta0, tb1, c01, 0, 0, 0);
    c10 = __builtin_amdgcn_mfma_f32_16x16x32_bf16(ta1, tb0, c10, 0, 0, 0);
    c11 = __builtin_amdgcn_mfma_f32_16x16x32_bf16(ta1, tb1, c11, 0, 0, 0);
    #pragma unroll
    for (int e = 0; e < 8; ++e) {
      const float v0 = bf2f((unsigned short)ta0[e]);
      const float v1 = bf2f((unsigned short)ta1[e]);
      const float v2 = bf2f((unsigned short)tb0[e]);
      const float v3 = bf2f((unsigned short)tb1[e]);
      ssA0 = fmaf(v0, v0, ssA0);
      ssA1 = fmaf(v1, v1, ssA1);
      ssB0 = fmaf(v2, v2, ssB0);
      ssB1 = fmaf(v3, v3, ssB1);
    }
  }
  ssA0 += __shfl_xor(ssA0, 16); ssA0 += __shfl_xor(ssA0, 32);
  ssA1 += __shfl_xor(ssA1, 16); ssA1 += __shfl_xor(ssA1, 32);
  ssB0 += __shfl_xor(ssB0, 16); ssB0 += __shfl_xor(ssB0, 32);
  ssB1 += __shfl_xor(ssB1, 16); ssB1 += __shfl_xor(ssB1, 32);
  if (gq == 0) {
    atomicAdd(&ssbuf[b * 96 + h * kCH + l15], ssA0);
    if (rA1 < kCH) atomicAdd(&ssbuf[b * 96 + h * kCH + rA1], ssA1);
    else if (rA1 < kQC) atomicAdd(&ssbuf[768 + b * 12 + h * 3 + (rA1 - kCH)], ssA1);
    atomicAdd(&ssbuf[384 + b * 96 + h * kCH + l15], ssB0);
    if (vB1) atomicAdd(&ssbuf[384 + b * 96 + h * kCH + rB1], ssB1);
  }
  float* wp = spart + ((size_t)((blockIdx.x * 16 + bh) * 4 + wave)) * 648;
  #pragma unroll
  for (int r = 0; r < 4; ++r) {
    const int row0 = gq * 4 + r, row1 = 16 + gq * 4 + r;
    wp[row0 * kCH + l15] = c00[r];
    if (16 + l15 < kCH) wp[row0 * kCH + 16 + l15] = c01[r];
    if (row1 < kQC) {
      wp[row1 * kCH + l15] = c10[r];
      if (16 + l15 < kCH) wp[row1 * kCH + 16 + l15] = c11[r];
    }
  }
}

// ---- sum partials, scale by rq*rk*temp, softmax over 24 ----
__global__ __launch_bounds__(256) void k_softmax(
    const float* __restrict__ spart, const float* __restrict__ ssbuf,
    const float* __restrict__ temp, float* __restrict__ attn) {
  const int row = blockIdx.x * 256 + threadIdx.x;
  if (row >= kB * kNH * kQC) return;
  const int bh = row / kQC, c = row - bh * kQC;
  const int b = bh >> 2, h = bh & 3;
  const float ssq = (c < kCH) ? ssbuf[b * 96 + h * kCH + c]
                              : ssbuf[768 + b * 12 + h * 3 + (c - kCH)];
  const float rq = 1.f / fmaxf(sqrtf(ssq), 1e-12f);
  const float t = temp[h];
  float l[kCH];
  #pragma unroll
  for (int d = 0; d < kCH; ++d) l[d] = 0.f;
  for (int s = 0; s < kQKSPLIT * 4; ++s) {
    const int split = s >> 2, wv = s & 3;
    const float* sp = spart + ((size_t)((split * 16 + bh) * 4 + wv)) * 648 + c * kCH;
    #pragma unroll
    for (int d = 0; d < kCH; ++d) l[d] += sp[d];
  }
  float mx = -1e30f;
  #pragma unroll
  for (int d = 0; d < kCH; ++d) {
    const float rk = 1.f / fmaxf(sqrtf(ssbuf[384 + b * 96 + h * kCH + d]), 1e-12f);
    l[d] = l[d] * rq * rk * t;
    mx = fmaxf(mx, l[d]);
  }
  float sum = 0.f;
  #pragma unroll
  for (int d = 0; d < kCH; ++d) { l[d] = __expf(l[d] - mx); sum += l[d]; }
  const float inv = 1.f / sum;
  float* arow = attn + (size_t)(bh * kQC + c) * kCH;
  #pragma unroll
  for (int d = 0; d < kCH; ++d) arow[d] = l[d] * inv;
}

// ---- attn @ v -> dead q/k planes; 4 px/thread, vector loads/stores ----
__global__ __launch_bounds__(256) void k_av(
    const float* __restrict__ attn, unsigned short* __restrict__ qkv_post) {
  const int h = blockIdx.y;
  const int t4 = blockIdx.x * 256 + threadIdx.x;
  const int b = t4 >> 14, p0 = (t4 & 16383) * 4;
  __shared__ float at[kQC * kCH];
  for (int idx = threadIdx.x; idx < kQC * kCH; idx += 256)
    at[idx] = attn[(size_t)(b * kNH + h) * kQC * kCH + idx];
  __syncthreads();
  float acc[kQC][4];
  #pragma unroll
  for (int c = 0; c < kQC; ++c)
    #pragma unroll
    for (int j = 0; j < 4; ++j) acc[c][j] = 0.f;
  for (int d = 0; d < kCH; ++d) {
    const ushortx4 v =
        *(const ushortx4*)&qkv_post[((size_t)b * kQKVC + 192 + h * kCH + d) * kHW + p0];
    float vv[4];
    #pragma unroll
    for (int j = 0; j < 4; ++j) vv[j] = bf2f(v[j]);
    #pragma unroll
    for (int c = 0; c < kQC; ++c) {
      const float a = at[c * kCH + d];
      #pragma unroll
      for (int j = 0; j < 4; ++j) acc[c][j] = fmaf(a, vv[j], acc[c][j]);
    }
  }
  #pragma unroll
  for (int c = 0; c < kQC; ++c) {
    ushortx4 o;
    #pragma unroll
    for (int j = 0; j < 4; ++j) o[j] = f2bf(acc[c][j]);
    *(ushortx4*)&qkv_post[((size_t)b * kQKVC + h * kQC + c) * kHW + p0] = o;
  }
}

extern "C" void kernel_launch(void* const* d_in, const int* in_sizes, int n_in,
                              void* d_out, int out_size, void* d_ws, size_t ws_size,
                              hipStream_t stream) {
  (void)in_sizes; (void)n_in;
  const float* x     = (const float*)d_in[0];
  const float* svp   = (const float*)d_in[1];
  const float* n1w   = (const float*)d_in[2];
  const float* n1b   = (const float*)d_in[3];
  const float* qkvw  = (const float*)d_in[4];
  const float* dww   = (const float*)d_in[5];
  const float* svpw  = (const float*)d_in[6];
  const float* temp  = (const float*)d_in[7];
  const float* projw = (const float*)d_in[8];
  const float* n2w   = (const float*)d_in[9];
  const float* n2b   = (const float*)d_in[10];
  const float* w1    = (const float*)d_in[11];
  const float* w2    = (const float*)d_in[12];
  const float* fw    = (const float*)d_in[13];
  float* outp = (float*)d_out;

  const size_t SZ_A = (size_t)kB * kQKVC * kHW * 2;   // 150,994,944
  const size_t SZ_C = (size_t)kB * kC * kHW * 2;      //  50,331,648
  const size_t NEED = (1u << 20) + SZ_A + SZ_C;       // 202,375,168 (proven OK)

  if (ws_size < NEED) {
    k_fill0_f32<<<(out_size + 255) / 256, 256, 0, stream>>>(outp, out_size);
    return;
  }

  char* ws = (char*)d_ws;
  float* attn  = (float*)(ws + 65536);
  float* ssbuf = (float*)(ws + 131072);
  unsigned short* qb  = (unsigned short*)(ws + 262144);
  unsigned short* pb  = (unsigned short*)(ws + 317440);
  unsigned short* w1b = (unsigned short*)(ws + 342016);
  unsigned short* w2b = (unsigned short*)(ws + 391168);
  unsigned short* fwb = (unsigned short*)(ws + 440320);
  unsigned short* A    = (unsigned short*)(ws + (1u << 20));           // xn1/qkv_post
  unsigned short* bufC = (unsigned short*)(ws + (1u << 20) + SZ_A);    // group out / svpq+spart / x2
  float* mu2 = (float*)(ws + (1u << 20) + 134u * 1048576u);  // dead v-planes (b=3) by proj time
  float* rs2 = (float*)(ws + (1u << 20) + 135u * 1048576u);
  unsigned short* x2   = bufC;
  unsigned short* svpq = bufC;                                    // 6.29MB
  float* spart = (float*)(ws + (1u << 20) + SZ_A + 8u * 1048576u); // 5.3MB

  k_wconv<<<444, 256, 0, stream>>>(qkvw, projw, w1, w2, fw, qb, pb, w1b, w2b, fwb);
  k_zero<<<4, 256, 0, stream>>>(ssbuf, 816);
  k_ln1_apply<<<kNP / 256, 256, 0, stream>>>(x, n1w, n1b, A);
  for (int grp = 0; grp < 3; ++grp) {
    k_gemm_qkv<<<dim3(kHW / 128, kB), 256, 0, stream>>>(A, qb, grp, bufC);
    k_dw<<<kB * kC * 16, 256, 0, stream>>>(bufC, dww, A, grp * kC);
  }
  k_svpq<<<kNP / 8 / 256, 256, 0, stream>>>(svp, svpw, svpq);
  k_qk<<<dim3(kQKSPLIT, 16), 256, 0, stream>>>(A, svpq, spart, ssbuf);
  k_softmax<<<2, 256, 0, stream>>>(spart, ssbuf, temp, attn);
  k_av<<<dim3(kNP / 4 / 256, kNH), 256, 0, stream>>>(attn, A);
  k_gemm_proj<<<dim3(kHW / 128, kB), 256, 0, stream>>>(A, pb, x, x2, mu2, rs2);
  k_gemm_gatefout<<<dim3(kHW / 128, kB), 256, 0, stream>>>(
      x2, mu2, rs2, n2w, n2b, w1b, w2b, fwb, outp);
}

// Round 8
// 618.768 us; speedup vs baseline: 1.2502x; 1.0331x over previous
//
#include <hip/hip_runtime.h>

// SAIGTransformer (f32 in/out, bf16 intermediates + MFMA GEMMs).
// ws layout (NEED = 202,375,168 B, proven previously):
//   [0,1MB): smalls: attn@64KB, ssbuf@128KB, bf16 weight copies @256KB..478KB
//   A @1MB, 151MB: xn1 (planes 192..287) -> qkv pre (planes 0..191) ->
//     qkv_post(288 planes bf16); LN2 stats @A+134MB (dead v-planes by proj)
//   C @1MB+151MB, 48MB: qkv grp0 pre -> svpq(6.3MB)+spart(@+8MB,5.3MB) -> x2
// R5 lesson: A-operands MUST stage via LDS (direct-global A = latency-bound).
// k_gemm_qkv3: B-tile (xn1) staged ONCE, 3 groups looped internally.
//   grp0->bufC, grp1->A[0:96], grp2->A[96:192]; dw order v,k,q.
// bf16 packing via v_cvt_pk_bf16_f32 (1 inst vs 4; same RNE rounding).

namespace {
constexpr int kB = 4;
constexpr int kC = 96;
constexpr int kHW = 65536;
constexpr int kNP = kB * kHW;
constexpr int kQKVC = 288;
constexpr int kNH = 4;
constexpr int kCH = 24;
constexpr int kQC = 27;
constexpr int kHID = 255;
constexpr int kSTR = 40;   // LDS k-stride: 32+8 pad, rows 80B (16B-aligned)
constexpr int kBST = 104;  // wide Bs stride: 96 k + 8 pad (208B rows, 16B-aligned)
constexpr int kQKSPLIT = 32;  // pixel splits in k_qk
}

typedef __attribute__((ext_vector_type(8))) short short8;
typedef __attribute__((ext_vector_type(8))) unsigned short ushort8;
typedef __attribute__((ext_vector_type(4))) unsigned short ushortx4;
typedef __attribute__((ext_vector_type(4))) float floatx4;
typedef __attribute__((ext_vector_type(4))) unsigned int uintx4;
typedef __attribute__((ext_vector_type(2))) unsigned int uintx2;

__device__ __forceinline__ float bf2f(unsigned short u) {
  return __uint_as_float(((unsigned int)u) << 16);
}
__device__ __forceinline__ unsigned short f2bf(float f) {
  unsigned int i = __float_as_uint(f);
  i += 0x7fffu + ((i >> 16) & 1u);
  return (unsigned short)(i >> 16);
}
// HW packed convert (RNE, same as f2bf): dst.lo=cvt(lo), dst.hi=cvt(hi)
__device__ __forceinline__ unsigned int pk2_bf16(float lo, float hi) {
  unsigned int r;
  asm("v_cvt_pk_bf16_f32 %0, %1, %2" : "=v"(r) : "v"(lo), "v"(hi));
  return r;
}
__device__ __forceinline__ unsigned short f2bf_fast(float f) {
  return (unsigned short)pk2_bf16(f, f);
}

__global__ void k_zero(float* __restrict__ p, int n) {
  const int i = blockIdx.x * blockDim.x + threadIdx.x;
  if (i < n) p[i] = 0.f;
}
__global__ void k_fill0_f32(float* __restrict__ p, int n) {
  const int i = blockIdx.x * blockDim.x + threadIdx.x;
  if (i < n) p[i] = 0.f;
}

// ---- one-shot weight conversion to bf16 (padded) ----
__global__ __launch_bounds__(256) void k_wconv(
    const float* __restrict__ qkvw, const float* __restrict__ projw,
    const float* __restrict__ w1, const float* __restrict__ w2,
    const float* __restrict__ fw, unsigned short* __restrict__ qb,
    unsigned short* __restrict__ pb, unsigned short* __restrict__ w1b,
    unsigned short* __restrict__ w2b, unsigned short* __restrict__ fwb) {
  int i = blockIdx.x * 256 + threadIdx.x;
  if (i < 27648) { qb[i] = f2bf(qkvw[i]); return; }
  i -= 27648;
  if (i < 12288) {
    const int r = i >> 7, k = i & 127;
    pb[i] = (k < 108) ? f2bf(projw[r * 108 + k]) : (unsigned short)0;
    return;
  }
  i -= 12288;
  if (i < 24576) { w1b[i] = (i < 24480) ? f2bf(w1[i]) : (unsigned short)0; return; }
  i -= 24576;
  if (i < 24576) { w2b[i] = (i < 24480) ? f2bf(w2[i]) : (unsigned short)0; return; }
  i -= 24576;
  {
    const int r = i >> 8, k = i & 255;
    fwb[i] = (k < 255) ? f2bf(fw[r * 255 + k]) : (unsigned short)0;
  }
}

// ---- LN1 fused stats+apply (single pass, values held in registers) ----
__global__ __launch_bounds__(256) void k_ln1_apply(
    const float* __restrict__ x, const float* __restrict__ nw,
    const float* __restrict__ nb, unsigned short* __restrict__ A) {
  const int pg = blockIdx.x * 256 + threadIdx.x;
  const int b = pg >> 16, p = pg & (kHW - 1);
  const float* xb = x + (size_t)b * kC * kHW + p;
  float v[kC];
  float s = 0.f, s2 = 0.f;
  #pragma unroll
  for (int c = 0; c < kC; ++c) {
    v[c] = xb[(size_t)c * kHW];
    s += v[c];
    s2 = fmaf(v[c], v[c], s2);
  }
  const float m = s * (1.f / kC);
  const float var = s2 * (1.f / kC) - m * m;
  const float rstd = rsqrtf(var + 1e-5f);
  unsigned short* ob = A + ((size_t)b * kQKVC + 192) * kHW + p;
  #pragma unroll
  for (int c = 0; c < kC; ++c) {
    ob[(size_t)c * kHW] = f2bf_fast((v[c] - m) * rstd * nw[c] + nb[c]);
  }
}

// ==== GEMM 1: all 3 qkv groups, B (xn1 96k x 128px) staged ONCE ====
// grp0 -> bufC; grp1 -> A planes [0,96); grp2 -> A planes [96,192).
// xn1 (planes 192..287) only READ; writes hit planes 0..191 -> no hazard.
__global__ __launch_bounds__(256) void k_gemm_qkv3(
    unsigned short* __restrict__ Abuf, const unsigned short* __restrict__ qb,
    unsigned short* __restrict__ bufC) {
  __shared__ __align__(16) unsigned short Bs[128 * kBST];  // 26,624 B
  __shared__ __align__(16) unsigned short As[96 * kSTR];   //  7,680 B
  const int tid = threadIdx.x;
  const int b = blockIdx.y;
  const int p0 = blockIdx.x * 128;
  const int wave = tid >> 6, lane = tid & 63, ln16 = lane & 15, quad = lane >> 4;
  const int rB = tid >> 3, c0 = (tid & 7) * 16;
  const int pos = rB ^ ((tid & 3) << 3);
  const int q0 = (quad ^ ((wave * 2) & 3)) << 3;
  const int q1 = (quad ^ ((wave * 2 + 1) & 3)) << 3;
  // stage B once: all 96 k planes of xn1
  #pragma unroll
  for (int ks = 0; ks < 3; ++ks) {
    const unsigned short* src =
        Abuf + ((size_t)b * kQKVC + 192 + ks * 32 + rB) * kHW + p0 + c0;
    const ushort8 u0 = ((const ushort8*)src)[0];
    const ushort8 u1 = ((const ushort8*)src)[1];
    #pragma unroll
    for (int e = 0; e < 8; ++e) {
      Bs[(c0 + e) * kBST + ks * 32 + pos] = u0[e];
      Bs[(c0 + 8 + e) * kBST + ks * 32 + pos] = u1[e];
    }
  }
  for (int grp = 0; grp < 3; ++grp) {
    floatx4 acc[6][2];
    #pragma unroll
    for (int i = 0; i < 6; ++i) { acc[i][0] = (floatx4)(0.f); acc[i][1] = (floatx4)(0.f); }
    for (int ks = 0; ks < 3; ++ks) {
      for (int idx = tid; idx < 384; idx += 256) {
        const int m = idx >> 2, ch = idx & 3;
        *(short8*)&As[m * kSTR + ch * 8] =
            *(const short8*)(qb + (size_t)(grp * 96 + m) * 96 + ks * 32 + ch * 8);
      }
      __syncthreads();  // As staged (covers Bs staging on first iteration)
      short8 bfr0 = *(const short8*)&Bs[(wave * 32 + ln16) * kBST + ks * 32 + q0];
      short8 bfr1 = *(const short8*)&Bs[(wave * 32 + 16 + ln16) * kBST + ks * 32 + q1];
      #pragma unroll
      for (int ms = 0; ms < 6; ++ms) {
        const short8 afr = *(const short8*)&As[(ms * 16 + ln16) * kSTR + quad * 8];
        acc[ms][0] = __builtin_amdgcn_mfma_f32_16x16x32_bf16(afr, bfr0, acc[ms][0], 0, 0, 0);
        acc[ms][1] = __builtin_amdgcn_mfma_f32_16x16x32_bf16(afr, bfr1, acc[ms][1], 0, 0, 0);
      }
      __syncthreads();  // protect As before next stage
    }
    unsigned short* ob = (grp == 0)
        ? bufC + (size_t)b * kC * kHW
        : Abuf + ((size_t)b * kQKVC + (grp == 1 ? 0 : 96)) * kHW;
    #pragma unroll
    for (int ms = 0; ms < 6; ++ms)
      #pragma unroll
      for (int ns = 0; ns < 2; ++ns)
        #pragma unroll
        for (int r = 0; r < 4; ++r) {
          const int R = ms * 16 + quad * 4 + r;
          const int P = p0 + wave * 32 + ns * 16 + ln16;
          ob[(size_t)R * kHW + P] = f2bf_fast(acc[ms][ns][r]);
        }
  }
}

// ==== GEMM 2: proj (M=96, K=108 pad 128), + x residual; LN2 stats fused ====
__global__ __launch_bounds__(256) void k_gemm_proj(
    const unsigned short* __restrict__ qkv_post, const unsigned short* __restrict__ pb,
    const float* __restrict__ x, unsigned short* __restrict__ x2,
    float* __restrict__ mu2, float* __restrict__ rs2) {
  __shared__ __align__(16) unsigned short As[96 * kSTR];
  __shared__ __align__(16) unsigned short Bs[128 * kSTR];
  const int tid = threadIdx.x;
  const int b = blockIdx.y;
  const int p0 = blockIdx.x * 128;
  const int wave = tid >> 6, lane = tid & 63, ln16 = lane & 15, quad = lane >> 4;
  floatx4 acc[6][2];
  #pragma unroll
  for (int i = 0; i < 6; ++i) { acc[i][0] = (floatx4)(0.f); acc[i][1] = (floatx4)(0.f); }
  const int rB = tid >> 3, c0 = (tid & 7) * 16;
  const int pos = rB ^ ((tid & 3) << 3);
  const int q0 = (quad ^ ((wave * 2) & 3)) << 3;
  const int q1 = (quad ^ ((wave * 2 + 1) & 3)) << 3;
  for (int ks = 0; ks < 4; ++ks) {
    const int k0 = ks * 32;
    for (int idx = tid; idx < 384; idx += 256) {
      const int m = idx >> 2, ch = idx & 3;
      *(short8*)&As[m * kSTR + ch * 8] =
          *(const short8*)(pb + (size_t)m * 128 + k0 + ch * 8);
    }
    {
      const int k = k0 + rB;
      if (k < 108) {
        const unsigned short* src = qkv_post + ((size_t)b * kQKVC + k) * kHW + p0 + c0;
        const ushort8 u0 = ((const ushort8*)src)[0];
        const ushort8 u1 = ((const ushort8*)src)[1];
        #pragma unroll
        for (int e = 0; e < 8; ++e) {
          Bs[(c0 + e) * kSTR + pos] = u0[e];
          Bs[(c0 + 8 + e) * kSTR + pos] = u1[e];
        }
      } else {
        #pragma unroll
        for (int e = 0; e < 16; ++e) Bs[(c0 + e) * kSTR + pos] = 0;
      }
    }
    __syncthreads();
    short8 bfr0 = *(const short8*)&Bs[(wave * 32 + ln16) * kSTR + q0];
    short8 bfr1 = *(const short8*)&Bs[(wave * 32 + 16 + ln16) * kSTR + q1];
    #pragma unroll
    for (int ms = 0; ms < 6; ++ms) {
      const short8 afr = *(const short8*)&As[(ms * 16 + ln16) * kSTR + quad * 8];
      acc[ms][0] = __builtin_amdgcn_mfma_f32_16x16x32_bf16(afr, bfr0, acc[ms][0], 0, 0, 0);
      acc[ms][1] = __builtin_amdgcn_mfma_f32_16x16x32_bf16(afr, bfr1, acc[ms][1], 0, 0, 0);
    }
    __syncthreads();
  }
  float s[2] = {0.f, 0.f}, s2[2] = {0.f, 0.f};
  #pragma unroll
  for (int ms = 0; ms < 6; ++ms)
    #pragma unroll
    for (int ns = 0; ns < 2; ++ns)
      #pragma unroll
      for (int r = 0; r < 4; ++r) {
        const int R = ms * 16 + quad * 4 + r;
        const int P = p0 + wave * 32 + ns * 16 + ln16;
        const size_t idx = ((size_t)b * kC + R) * kHW + P;
        const float val = acc[ms][ns][r] + x[idx];
        x2[idx] = f2bf_fast(val);
        s[ns] += val;
        s2[ns] = fmaf(val, val, s2[ns]);
      }
  #pragma unroll
  for (int ns = 0; ns < 2; ++ns) {
    float a = s[ns], c = s2[ns];
    a += __shfl_xor(a, 16); a += __shfl_xor(a, 32);
    c += __shfl_xor(c, 16); c += __shfl_xor(c, 32);
    if (quad == 0) {
      const int P = p0 + wave * 32 + ns * 16 + ln16;
      const float m = a * (1.f / kC);
      mu2[(b << 16) + P] = m;
      rs2[(b << 16) + P] = rsqrtf(c * (1.f / kC) - m * m + 1e-5f);
    }
  }
}

// ==== GEMM 3+4 fused: gate -> Gs LDS -> fout. LDS = 54,272 B (3 blocks/CU). ====
__global__ __launch_bounds__(256) void k_gemm_gatefout(
    const unsigned short* __restrict__ x2, const float* __restrict__ mu_buf,
    const float* __restrict__ rs_buf, const float* __restrict__ nw,
    const float* __restrict__ nb, const unsigned short* __restrict__ w1b,
    const unsigned short* __restrict__ w2b, const unsigned short* __restrict__ fwb,
    float* __restrict__ out) {
  __shared__ __align__(16) unsigned short Bs[128 * kBST];  // 26624 B
  __shared__ __align__(16) unsigned short As[128 * kSTR];  // 10240 B
  __shared__ __align__(16) unsigned int Gs[128 * 32];      // 16384 B
  __shared__ float mus[128], rss[128];                     //  1024 B
  const int tid = threadIdx.x;
  const int b = blockIdx.y;
  const int p0 = blockIdx.x * 128;
  if (tid < 128) {
    mus[tid] = mu_buf[(b << 16) + p0 + tid];
    rss[tid] = rs_buf[(b << 16) + p0 + tid];
  }
  __syncthreads();
  const int wave = tid >> 6, lane = tid & 63, ln16 = lane & 15, quad = lane >> 4;
  const int rB = tid >> 3, c0 = (tid & 7) * 16;
  const int pos = rB ^ ((tid & 3) << 3);
  const int q0 = (quad ^ ((wave * 2) & 3)) << 3;
  const int q1 = (quad ^ ((wave * 2 + 1) & 3)) << 3;
  const int l7 = ln16 & 7;
  // stage B once: all 96 k, LN2 applied
  #pragma unroll
  for (int ks = 0; ks < 3; ++ks) {
    const int k = ks * 32 + rB;
    const float wk = nw[k], bk = nb[k];
    const unsigned short* src = x2 + ((size_t)b * kC + k) * kHW + p0 + c0;
    const ushort8 u0 = ((const ushort8*)src)[0];
    const ushort8 u1 = ((const ushort8*)src)[1];
    #pragma unroll
    for (int e = 0; e < 8; ++e) {
      const int n0 = c0 + e, n1 = c0 + 8 + e;
      Bs[n0 * kBST + ks * 32 + pos] =
          f2bf_fast((bf2f(u0[e]) - mus[n0]) * rss[n0] * wk + bk);
      Bs[n1 * kBST + ks * 32 + pos] =
          f2bf_fast((bf2f(u1[e]) - mus[n1]) * rss[n1] * wk + bk);
    }
  }
  floatx4 facc[6][2];
  #pragma unroll
  for (int i = 0; i < 6; ++i) { facc[i][0] = (floatx4)(0.f); facc[i][1] = (floatx4)(0.f); }
  for (int grp = 0; grp < 4; ++grp) {
    const int i0 = grp * 64;
    floatx4 acc[8][2];
    #pragma unroll
    for (int i = 0; i < 8; ++i) { acc[i][0] = (floatx4)(0.f); acc[i][1] = (floatx4)(0.f); }
    // --- gate GEMM over K=96 ---
    #pragma unroll
    for (int ks = 0; ks < 3; ++ks) {
      for (int idx = tid; idx < 512; idx += 256) {
        const int m = idx >> 2, ch = idx & 3;
        const int ii = i0 + (m & 63);  // rows 192..255 valid: row 255 is zero
        const unsigned short* wsrc =
            ((m < 64) ? w1b : w2b) + (size_t)ii * 96 + ks * 32 + ch * 8;
        *(short8*)&As[m * kSTR + ch * 8] = *(const short8*)wsrc;
      }
      __syncthreads();  // As staged (also covers Bs on first iter / Gs free)
      short8 bfr0 = *(const short8*)&Bs[(wave * 32 + ln16) * kBST + ks * 32 + q0];
      short8 bfr1 = *(const short8*)&Bs[(wave * 32 + 16 + ln16) * kBST + ks * 32 + q1];
      #pragma unroll
      for (int ms = 0; ms < 8; ++ms) {
        const short8 afr = *(const short8*)&As[(ms * 16 + ln16) * kSTR + quad * 8];
        acc[ms][0] = __builtin_amdgcn_mfma_f32_16x16x32_bf16(afr, bfr0, acc[ms][0], 0, 0, 0);
        acc[ms][1] = __builtin_amdgcn_mfma_f32_16x16x32_bf16(afr, bfr1, acc[ms][1], 0, 0, 0);
      }
      __syncthreads();  // protect As before next stage
    }
    // --- gate epilogue -> Gs (dword-packed, block-swizzled; row 255 -> 0) ---
    #pragma unroll
    for (int ms = 0; ms < 4; ++ms)
      #pragma unroll
      for (int ns = 0; ns < 2; ++ns) {
        const int pl = wave * 32 + ns * 16 + ln16;
        #pragma unroll
        for (int rr = 0; rr < 2; ++rr) {
          float gv[2];
          #pragma unroll
          for (int h = 0; h < 2; ++h) {
            const float p1 = acc[ms][ns][rr * 2 + h], p2 = acc[ms + 4][ns][rr * 2 + h];
            const float sig = __builtin_amdgcn_rcpf(1.f + __expf(-p2));
            const float targ = p1 * fmaf(p1 * p1, 0.0713548f, 1.5957691f);
            const float gel = p1 * __builtin_amdgcn_rcpf(1.f + __expf(-targ));
            gv[h] = fmaf(p1, sig, p2 * gel);
          }
          const int dj = ms * 8 + quad * 2 + rr;       // dword idx in row (0..31)
          const int djs = dj ^ (l7 << 2);              // swizzle 4-dword blocks
          Gs[pl * 32 + djs] = pk2_bf16(gv[0], gv[1]);
        }
      }
    __syncthreads();  // Gs complete
    // --- fout partial: K window [i0, i0+64) from Gs ---
    #pragma unroll
    for (int ksub = 0; ksub < 2; ++ksub) {
      for (int idx = tid; idx < 384; idx += 256) {
        const int m = idx >> 2, ch = idx & 3;
        *(short8*)&As[m * kSTR + ch * 8] =
            *(const short8*)(fwb + (size_t)m * 256 + i0 + ksub * 32 + ch * 8);
      }
      __syncthreads();  // As staged
      const int bka = ((ksub * 4 + quad) ^ l7) * 4;
      const short8 bf0 = *(const short8*)&Gs[(wave * 32 + ln16) * 32 + bka];
      const short8 bf1 = *(const short8*)&Gs[(wave * 32 + 16 + ln16) * 32 + bka];
      #pragma unroll
      for (int ms = 0; ms < 6; ++ms) {
        const short8 afr = *(const short8*)&As[(ms * 16 + ln16) * kSTR + quad * 8];
        facc[ms][0] = __builtin_amdgcn_mfma_f32_16x16x32_bf16(afr, bf0, facc[ms][0], 0, 0, 0);
        facc[ms][1] = __builtin_amdgcn_mfma_f32_16x16x32_bf16(afr, bf1, facc[ms][1], 0, 0, 0);
      }
      __syncthreads();  // As/Gs free for next stage/grp
    }
  }
  // --- fout epilogue: + x2 residual, f32 out ---
  #pragma unroll
  for (int ms = 0; ms < 6; ++ms)
    #pragma unroll
    for (int ns = 0; ns < 2; ++ns)
      #pragma unroll
      for (int r = 0; r < 4; ++r) {
        const int R = ms * 16 + quad * 4 + r;
        const int P = p0 + wave * 32 + ns * 16 + ln16;
        const size_t idx = ((size_t)b * kC + R) * kHW + P;
        out[idx] = facc[ms][ns][r] + bf2f(x2[idx]);
      }
}

// ---- depthwise 3x3 SAME: 16 outputs/thread (rows y,y+1 x 8 px) ----
// src plane = buf[(b*bstride + sbase + chl)*kHW]; dst plane = gbase+chl.
__global__ __launch_bounds__(256) void k_dw(
    const unsigned short* __restrict__ buf, int bstride, int sbase,
    const float* __restrict__ dww, unsigned short* __restrict__ qkv_post, int gbase) {
  const int blk = blockIdx.x;
  const int plane = blk >> 4;            // b*kC + chl
  const int yg = (blk & 15) * 16;
  const int b = plane / kC, chl = plane % kC;
  const int t = threadIdx.x;
  const int y = yg + (t >> 5) * 2;       // rows y, y+1
  const int x0 = (t & 31) * 8;
  const unsigned short* in = buf + ((size_t)(b * bstride + sbase + chl)) * kHW;
  float w[9];
  #pragma unroll
  for (int i = 0; i < 9; ++i) w[i] = dww[(size_t)(gbase + chl) * 9 + i];
  float acc0[8], acc1[8];
  #pragma unroll
  for (int j = 0; j < 8; ++j) { acc0[j] = 0.f; acc1[j] = 0.f; }
  #pragma unroll
  for (int dy = -1; dy <= 2; ++dy) {
    const int yy = y + dy;
    if (yy < 0 || yy > 255) continue;
    const unsigned short* rp = in + yy * 256;
    float f[10];
    const ushort8 v = *(const ushort8*)(rp + x0);
    #pragma unroll
    for (int e = 0; e < 8; ++e) f[e + 1] = bf2f(v[e]);
    f[0] = (x0 > 0) ? bf2f(rp[x0 - 1]) : 0.f;
    f[9] = (x0 < 248) ? bf2f(rp[x0 + 8]) : 0.f;
    if (dy <= 1) {
      const float w0 = w[(dy + 1) * 3], w1 = w[(dy + 1) * 3 + 1], w2 = w[(dy + 1) * 3 + 2];
      #pragma unroll
      for (int j = 0; j < 8; ++j)
        acc0[j] = fmaf(w0, f[j], fmaf(w1, f[j + 1], fmaf(w2, f[j + 2], acc0[j])));
    }
    if (dy >= 0) {
      const float w0 = w[dy * 3], w1 = w[dy * 3 + 1], w2 = w[dy * 3 + 2];
      #pragma unroll
      for (int j = 0; j < 8; ++j)
        acc1[j] = fmaf(w0, f[j], fmaf(w1, f[j + 1], fmaf(w2, f[j + 2], acc1[j])));
    }
  }
  unsigned short* op = qkv_post + ((size_t)b * kQKVC + gbase + chl) * kHW + y * 256 + x0;
  uintx4 o0, o1;
  #pragma unroll
  for (int j = 0; j < 4; ++j) {
    o0[j] = pk2_bf16(acc0[j * 2], acc0[j * 2 + 1]);
    o1[j] = pk2_bf16(acc1[j * 2], acc1[j * 2 + 1]);
  }
  *(uintx4*)op = o0;
  *(uintx4*)(op + 256) = o1;
}

// ---- svp_q = svpw @ svp, bf16 planes [b*12 + j][kHW]; 8 px/thread ----
__global__ __launch_bounds__(256) void k_svpq(
    const float* __restrict__ svp, const float* __restrict__ svpw,
    unsigned short* __restrict__ svpq) {
  const int t8 = blockIdx.x * 256 + threadIdx.x;
  const int b = t8 >> 13, p0 = (t8 & 8191) * 8;
  float s0[8], s1[8], s2v[8];
  #pragma unroll
  for (int j = 0; j < 8; ++j) {
    s0[j] = svp[((size_t)b * 3 + 0) * kHW + p0 + j];
    s1[j] = svp[((size_t)b * 3 + 1) * kHW + p0 + j];
    s2v[j] = svp[((size_t)b * 3 + 2) * kHW + p0 + j];
  }
  #pragma unroll
  for (int jj = 0; jj < 12; ++jj) {
    const float w0 = svpw[jj * 3], w1 = svpw[jj * 3 + 1], w2 = svpw[jj * 3 + 2];
    uintx4 o;
    #pragma unroll
    for (int j = 0; j < 4; ++j) {
      const float a = fmaf(w2, s2v[j * 2], fmaf(w1, s1[j * 2], w0 * s0[j * 2]));
      const float c = fmaf(w2, s2v[j * 2 + 1], fmaf(w1, s1[j * 2 + 1], w0 * s0[j * 2 + 1]));
      o[j] = pk2_bf16(a, c);
    }
    *(uintx4*)&svpq[((size_t)b * 12 + jj) * kHW + p0] = o;
  }
}

// ---- MFMA QK^T reduction over pixels; fused row sum-of-squares (rnorm) ----
__global__ __launch_bounds__(256) void k_qk(
    const unsigned short* __restrict__ qkv_post, const unsigned short* __restrict__ svpq,
    float* __restrict__ spart, float* __restrict__ ssbuf) {
  const int bh = blockIdx.y, b = bh >> 2, h = bh & 3;
  const int tid = threadIdx.x;
  const int wave = tid >> 6, lane = tid & 63;
  const int l15 = lane & 15, gq = lane >> 4;
  const int pstart = blockIdx.x * 2048 + wave * 512;
  constexpr int NCH = 16;  // 512 px / 32

  const unsigned short* pA0 =
      qkv_post + ((size_t)b * kQKVC + h * kCH + l15) * kHW + gq * 8;
  const unsigned short* pB0 =
      qkv_post + ((size_t)b * kQKVC + 96 + h * kCH + l15) * kHW + gq * 8;
  const int rA1 = 16 + l15, rB1 = 16 + l15;
  const bool vA1 = (rA1 < kQC), vB1 = (rB1 < kCH);
  const unsigned short* pA1 =
      (rA1 < kCH) ? qkv_post + ((size_t)b * kQKVC + h * kCH + rA1) * kHW + gq * 8
      : (rA1 < kQC) ? svpq + ((size_t)(b * 12 + h * 3 + (rA1 - kCH))) * kHW + gq * 8
                    : pA0;
  const unsigned short* pB1 =
      vB1 ? qkv_post + ((size_t)b * kQKVC + 96 + h * kCH + rB1) * kHW + gq * 8 : pB0;

  floatx4 c00 = (floatx4)(0.f), c01 = (floatx4)(0.f);
  floatx4 c10 = (floatx4)(0.f), c11 = (floatx4)(0.f);
  float ssA0 = 0.f, ssA1 = 0.f, ssB0 = 0.f, ssB1 = 0.f;
  const short8 kZ = (short8)(short)0;

  short8 a0 = *(const short8*)(pA0 + pstart);
  short8 b0 = *(const short8*)(pB0 + pstart);
  short8 a1 = vA1 ? *(const short8*)(pA1 + pstart) : kZ;
  short8 b1 = vB1 ? *(const short8*)(pB1 + pstart) : kZ;
  for (int c = 0; c < NCH; ++c) {
    const short8 ta0 = a0, tb0 = b0, ta1 = a1, tb1 = b1;
    if (c + 1 < NCH) {
      const int pn = pstart + (c + 1) * 32;
      a0 = *(const short8*)(pA0 + pn);
      b0 = *(const short8*)(pB0 + pn);
      a1 = vA1 ? *(const short8*)(pA1 + pn) : kZ;
      b1 = vB1 ? *(const short8*)(pB1 + pn) : kZ;
    }
    c00 = __builtin_amdgcn_mfma_f32_16x16x32_bf16(ta0, tb0, c00, 0, 0, 0);
    c01 = __builtin_amdgcn_mfma_f32_16x16x32_bf16(ta0, tb1, c01, 0, 0, 0);
    c10 = __builtin_amdgcn_mfma_f32_16x16x32_bf16(ta1, tb0, c10, 0, 0, 0);
    c11 = __builtin_amdgcn_mfma_f32_16x16x32_bf16(ta1, tb1, c11, 0, 0, 0);
    #pragma unroll
    for (int e = 0; e < 8; ++e) {
      const float v0 = bf2f((unsigned short)ta0[e]);
      const float v1 = bf2f((unsigned short)ta1[e]);
      const float v2 = bf2f((unsigned short)tb0[e]);
      const float v3 = bf2f((unsigned short)tb1[e]);
      ssA0 = fmaf(v0, v0, ssA0);
      ssA1 = fmaf(v1, v1, ssA1);
      ssB0 = fmaf(v2, v2, ssB0);
      ssB1 = fmaf(v3, v3, ssB1);
    }
  }
  ssA0 += __shfl_xor(ssA0, 16); ssA0 += __shfl_xor(ssA0, 32);
  ssA1 += __shfl_xor(ssA1, 16); ssA1 += __shfl_xor(ssA1, 32);
  ssB0 += __shfl_xor(ssB0, 16); ssB0 += __shfl_xor(ssB0, 32);
  ssB1 += __shfl_xor(ssB1, 16); ssB1 += __shfl_xor(ssB1, 32);
  if (gq == 0) {
    atomicAdd(&ssbuf[b * 96 + h * kCH + l15], ssA0);
    if (rA1 < kCH) atomicAdd(&ssbuf[b * 96 + h * kCH + rA1], ssA1);
    else if (rA1 < kQC) atomicAdd(&ssbuf[768 + b * 12 + h * 3 + (rA1 - kCH)], ssA1);
    atomicAdd(&ssbuf[384 + b * 96 + h * kCH + l15], ssB0);
    if (vB1) atomicAdd(&ssbuf[384 + b * 96 + h * kCH + rB1], ssB1);
  }
  float* wp = spart + ((size_t)((blockIdx.x * 16 + bh) * 4 + wave)) * 648;
  #pragma unroll
  for (int r = 0; r < 4; ++r) {
    const int row0 = gq * 4 + r, row1 = 16 + gq * 4 + r;
    wp[row0 * kCH + l15] = c00[r];
    if (16 + l15 < kCH) wp[row0 * kCH + 16 + l15] = c01[r];
    if (row1 < kQC) {
      wp[row1 * kCH + l15] = c10[r];
      if (16 + l15 < kCH) wp[row1 * kCH + 16 + l15] = c11[r];
    }
  }
}

// ---- sum partials, scale by rq*rk*temp, softmax over 24 ----
__global__ __launch_bounds__(256) void k_softmax(
    const float* __restrict__ spart, const float* __restrict__ ssbuf,
    const float* __restrict__ temp, float* __restrict__ attn) {
  const int row = blockIdx.x * 256 + threadIdx.x;
  if (row >= kB * kNH * kQC) return;
  const int bh = row / kQC, c = row - bh * kQC;
  const int b = bh >> 2, h = bh & 3;
  const float ssq = (c < kCH) ? ssbuf[b * 96 + h * kCH + c]
                              : ssbuf[768 + b * 12 + h * 3 + (c - kCH)];
  const float rq = 1.f / fmaxf(sqrtf(ssq), 1e-12f);
  const float t = temp[h];
  float l[kCH];
  #pragma unroll
  for (int d = 0; d < kCH; ++d) l[d] = 0.f;
  for (int s = 0; s < kQKSPLIT * 4; ++s) {
    const int split = s >> 2, wv = s & 3;
    const float* sp = spart + ((size_t)((split * 16 + bh) * 4 + wv)) * 648 + c * kCH;
    #pragma unroll
    for (int d = 0; d < kCH; ++d) l[d] += sp[d];
  }
  float mx = -1e30f;
  #pragma unroll
  for (int d = 0; d < kCH; ++d) {
    const float rk = 1.f / fmaxf(sqrtf(ssbuf[384 + b * 96 + h * kCH + d]), 1e-12f);
    l[d] = l[d] * rq * rk * t;
    mx = fmaxf(mx, l[d]);
  }
  float sum = 0.f;
  #pragma unroll
  for (int d = 0; d < kCH; ++d) { l[d] = __expf(l[d] - mx); sum += l[d]; }
  const float inv = 1.f / sum;
  float* arow = attn + (size_t)(bh * kQC + c) * kCH;
  #pragma unroll
  for (int d = 0; d < kCH; ++d) arow[d] = l[d] * inv;
}

// ---- attn @ v -> dead q/k planes; 4 px/thread, vector loads/stores ----
__global__ __launch_bounds__(256) void k_av(
    const float* __restrict__ attn, unsigned short* __restrict__ qkv_post) {
  const int h = blockIdx.y;
  const int t4 = blockIdx.x * 256 + threadIdx.x;
  const int b = t4 >> 14, p0 = (t4 & 16383) * 4;
  __shared__ float at[kQC * kCH];
  for (int idx = threadIdx.x; idx < kQC * kCH; idx += 256)
    at[idx] = attn[(size_t)(b * kNH + h) * kQC * kCH + idx];
  __syncthreads();
  float acc[kQC][4];
  #pragma unroll
  for (int c = 0; c < kQC; ++c)
    #pragma unroll
    for (int j = 0; j < 4; ++j) acc[c][j] = 0.f;
  for (int d = 0; d < kCH; ++d) {
    const ushortx4 v =
        *(const ushortx4*)&qkv_post[((size_t)b * kQKVC + 192 + h * kCH + d) * kHW + p0];
    float vv[4];
    #pragma unroll
    for (int j = 0; j < 4; ++j) vv[j] = bf2f(v[j]);
    #pragma unroll
    for (int c = 0; c < kQC; ++c) {
      const float a = at[c * kCH + d];
      #pragma unroll
      for (int j = 0; j < 4; ++j) acc[c][j] = fmaf(a, vv[j], acc[c][j]);
    }
  }
  #pragma unroll
  for (int c = 0; c < kQC; ++c) {
    uintx2 o;
    o[0] = pk2_bf16(acc[c][0], acc[c][1]);
    o[1] = pk2_bf16(acc[c][2], acc[c][3]);
    *(uintx2*)&qkv_post[((size_t)b * kQKVC + h * kQC + c) * kHW + p0] = o;
  }
}

extern "C" void kernel_launch(void* const* d_in, const int* in_sizes, int n_in,
                              void* d_out, int out_size, void* d_ws, size_t ws_size,
                              hipStream_t stream) {
  (void)in_sizes; (void)n_in;
  const float* x     = (const float*)d_in[0];
  const float* svp   = (const float*)d_in[1];
  const float* n1w   = (const float*)d_in[2];
  const float* n1b   = (const float*)d_in[3];
  const float* qkvw  = (const float*)d_in[4];
  const float* dww   = (const float*)d_in[5];
  const float* svpw  = (const float*)d_in[6];
  const float* temp  = (const float*)d_in[7];
  const float* projw = (const float*)d_in[8];
  const float* n2w   = (const float*)d_in[9];
  const float* n2b   = (const float*)d_in[10];
  const float* w1    = (const float*)d_in[11];
  const float* w2    = (const float*)d_in[12];
  const float* fw    = (const float*)d_in[13];
  float* outp = (float*)d_out;

  const size_t SZ_A = (size_t)kB * kQKVC * kHW * 2;   // 150,994,944
  const size_t SZ_C = (size_t)kB * kC * kHW * 2;      //  50,331,648
  const size_t NEED = (1u << 20) + SZ_A + SZ_C;       // 202,375,168 (proven OK)

  if (ws_size < NEED) {
    k_fill0_f32<<<(out_size + 255) / 256, 256, 0, stream>>>(outp, out_size);
    return;
  }

  char* ws = (char*)d_ws;
  float* attn  = (float*)(ws + 65536);
  float* ssbuf = (float*)(ws + 131072);
  unsigned short* qb  = (unsigned short*)(ws + 262144);
  unsigned short* pb  = (unsigned short*)(ws + 317440);
  unsigned short* w1b = (unsigned short*)(ws + 342016);
  unsigned short* w2b = (unsigned short*)(ws + 391168);
  unsigned short* fwb = (unsigned short*)(ws + 440320);
  unsigned short* A    = (unsigned short*)(ws + (1u << 20));           // xn1/qkv pre+post
  unsigned short* bufC = (unsigned short*)(ws + (1u << 20) + SZ_A);    // grp0 pre / svpq+spart / x2
  float* mu2 = (float*)(ws + (1u << 20) + 134u * 1048576u);  // dead v-planes (b=3) by proj time
  float* rs2 = (float*)(ws + (1u << 20) + 135u * 1048576u);
  unsigned short* x2   = bufC;
  unsigned short* svpq = bufC;                                    // 6.29MB
  float* spart = (float*)(ws + (1u << 20) + SZ_A + 8u * 1048576u); // 5.3MB

  k_wconv<<<444, 256, 0, stream>>>(qkvw, projw, w1, w2, fw, qb, pb, w1b, w2b, fwb);
  k_zero<<<4, 256, 0, stream>>>(ssbuf, 816);
  k_ln1_apply<<<kNP / 256, 256, 0, stream>>>(x, n1w, n1b, A);
  k_gemm_qkv3<<<dim3(kHW / 128, kB), 256, 0, stream>>>(A, qb, bufC);
  // dw order v,k,q: each source consumed before its buffer is overwritten
  k_dw<<<kB * kC * 16, 256, 0, stream>>>(A, kQKVC, 96, dww, A, 192);  // v
  k_dw<<<kB * kC * 16, 256, 0, stream>>>(A, kQKVC, 0, dww, A, 96);    // k
  k_dw<<<kB * kC * 16, 256, 0, stream>>>(bufC, kC, 0, dww, A, 0);     // q
  k_svpq<<<kNP / 8 / 256, 256, 0, stream>>>(svp, svpw, svpq);
  k_qk<<<dim3(kQKSPLIT, 16), 256, 0, stream>>>(A, svpq, spart, ssbuf);
  k_softmax<<<2, 256, 0, stream>>>(spart, ssbuf, temp, attn);
  k_av<<<dim3(kNP / 4 / 256, kNH), 256, 0, stream>>>(attn, A);
  k_gemm_proj<<<dim3(kHW / 128, kB), 256, 0, stream>>>(A, pb, x, x2, mu2, rs2);
  k_gemm_gatefout<<<dim3(kHW / 128, kB), 256, 0, stream>>>(
      x2, mu2, rs2, n2w, n2b, w1b, w2b, fwb, outp);
}